// Round 1
// baseline (732.735 us; speedup 1.0000x reference)
//
#include <hip/hip_runtime.h>
#include <stdint.h>

#define NA   100800
#define NIMG 8
#define TOPK 2048
typedef unsigned long long u64;

// ---------------- K0: zero per-image counters ----------------
__global__ void k0_init(int* counts) {
    int t = threadIdx.x;
    if (t < NIMG) counts[t] = 0;
}

// ---------------- K1: filter + compact sort keys ----------------
// key = (conf_bits << 32) | (0xFFFFFFFF - idx)  -> desc key == (conf desc, idx asc)
__global__ void k1_compact(const float* __restrict__ pred,
                           u64* __restrict__ cand, int* __restrict__ counts) {
    int m = blockIdx.y;
    int a = blockIdx.x * 256 + threadIdx.x;
    bool valid = false;
    u64 key = 0;
    if (a < NA) {
        const float* row = pred + ((size_t)m * NA + a) * 16;
        float obj  = row[4];
        float x15  = row[15];
        float conf = __fmul_rn(x15, obj);          // exact same single f32 mul as ref
        if (obj > 0.5f && conf > 0.5f) {
            valid = true;
            key = ((u64)__float_as_uint(conf) << 32) | (u64)(0xFFFFFFFFu - (unsigned)a);
        }
    }
    u64 bal = __ballot(valid);
    if (bal == 0ull) return;
    int lane   = threadIdx.x & 63;
    int leader = __ffsll(bal) - 1;
    int total  = __popcll(bal);
    int base   = 0;
    if (lane == leader) base = atomicAdd(&counts[m], total);
    base = __shfl(base, leader);
    if (valid) {
        int rank = __popcll(bal & ((1ull << lane) - 1ull));
        cand[(size_t)m * NA + base + rank] = key;
    }
}

// ---------------- K2: per-image streaming bitonic top-2048 (sorted desc) ----------------
__global__ __launch_bounds__(1024) void k2_select(const u64* __restrict__ cand,
                                                  const int* __restrict__ counts,
                                                  u64* __restrict__ sel) {
    __shared__ u64 buf[4096];
    int m   = blockIdx.x;
    int tid = threadIdx.x;
    int count = counts[m];
    const u64* c = cand + (size_t)m * NA;

    for (int i = tid; i < TOPK; i += 1024) buf[i] = 0ull;   // sentinel (below all real keys)

    int nch = (count + TOPK - 1) / TOPK;
    for (int ch = 0; ch < nch; ++ch) {
        for (int i = tid; i < TOPK; i += 1024) {
            int g = ch * TOPK + i;
            buf[TOPK + i] = (g < count) ? c[g] : 0ull;
        }
        // full bitonic sort of 4096, descending
        for (int k = 2; k <= 4096; k <<= 1) {
            for (int j = k >> 1; j > 0; j >>= 1) {
                __syncthreads();
                #pragma unroll
                for (int i = tid; i < 4096; i += 1024) {
                    int l = i ^ j;
                    if (l > i) {
                        u64 A = buf[i], B = buf[l];
                        bool up = ((i & k) == 0);
                        if (up ? (A < B) : (A > B)) { buf[i] = B; buf[l] = A; }
                    }
                }
            }
        }
        __syncthreads();   // top 2048 now in buf[0..2047]
    }
    for (int i = tid; i < TOPK; i += 1024) sel[(size_t)m * TOPK + i] = buf[i];
}

// ---------------- K3: stage xyxy boxes for selected slots ----------------
__global__ void k3_boxes(const float* __restrict__ pred, const u64* __restrict__ sel,
                         float4* __restrict__ boxes) {
    int gid = blockIdx.x * 256 + threadIdx.x;
    if (gid >= NIMG * TOPK) return;
    int m = gid >> 11;
    u64 key = sel[gid];
    float4 b = make_float4(0.f, 0.f, 0.f, 0.f);
    if (key) {
        unsigned idx = 0xFFFFFFFFu - (unsigned)(key & 0xFFFFFFFFull);
        const float4* rv = reinterpret_cast<const float4*>(pred + ((size_t)m * NA + idx) * 16);
        float4 v = rv[0];                       // [xc, yc, w, h]
        float hw = __fmul_rn(v.z, 0.5f), hh = __fmul_rn(v.w, 0.5f);
        b.x = __fsub_rn(v.x, hw);
        b.y = __fsub_rn(v.y, hh);
        b.z = __fadd_rn(v.x, hw);
        b.w = __fadd_rn(v.y, hh);
    }
    boxes[gid] = b;
}

// ---------------- K4: 2048x2048 suppression bitmask (iou > 0.45) ----------------
// block = 1024 thr = 32 rows x 32 words; half-wave shares b2 address (LDS broadcast)
__global__ __launch_bounds__(1024) void k4_masks(const float4* __restrict__ boxes,
                                                 u64* __restrict__ maskm) {
    __shared__ float4 bx[TOPK];
    int m   = blockIdx.y;
    int grp = blockIdx.x;                       // 64 groups of 32 rows
    for (int i = threadIdx.x; i < TOPK; i += 1024)
        bx[i] = boxes[(size_t)m * TOPK + i];
    __syncthreads();

    int il = threadIdx.x & 31;
    int w  = threadIdx.x >> 5;
    int i  = grp * 32 + il;
    float4 b1 = bx[i];
    float a1 = __fmul_rn(__fsub_rn(b1.z, b1.x), __fsub_rn(b1.w, b1.y));
    u64 bits = 0ull;
    #pragma unroll 4
    for (int jj = 0; jj < 64; ++jj) {
        float4 b2 = bx[w * 64 + jj];
        float a2 = __fmul_rn(__fsub_rn(b2.z, b2.x), __fsub_rn(b2.w, b2.y));
        float iw = fmaxf(__fsub_rn(fminf(b1.z, b2.z), fmaxf(b1.x, b2.x)), 0.f);
        float ih = fmaxf(__fsub_rn(fminf(b1.w, b2.w), fmaxf(b1.y, b2.y)), 0.f);
        float inter = __fmul_rn(iw, ih);
        float uni   = __fsub_rn(__fadd_rn(a1, a2), inter);   // (a1+a2)-inter, ref order
        float iou   = __fdiv_rn(inter, uni);
        if (iou > 0.45f) bits |= (1ull << jj);
    }
    maskm[((size_t)m * TOPK + i) * 32 + w] = bits;
}

// ---------------- K5: sequential greedy scan (1 wave / image) ----------------
__global__ void k5_nms(const u64* __restrict__ sel, const u64* __restrict__ maskm,
                       u64* __restrict__ keepmask) {
    int m = blockIdx.x;
    int lane = threadIdx.x;                     // 64 threads = 1 wave
    // valid bitmap: lane l holds word l (rows l*64 .. l*64+63)
    u64 vw = 0ull;
    for (int w = 0; w < 32; ++w) {
        u64 bal = __ballot(sel[(size_t)m * TOPK + w * 64 + lane] != 0ull);
        if (lane == w) vw = bal;
    }
    int wl = lane & 31;
    const u64* mb = maskm + (size_t)m * TOPK * 32 + wl;
    u64 remv = 0ull, kb = 0ull;
    u64 cur[8];
    #pragma unroll
    for (int k = 0; k < 8; ++k) cur[k] = mb[(size_t)k * 32];

    for (int b = 0; b < TOPK / 8; ++b) {
        u64 nxt[8];
        if (b + 1 < TOPK / 8) {
            #pragma unroll
            for (int k = 0; k < 8; ++k) nxt[k] = mb[(size_t)((b + 1) * 8 + k) * 32];
        } else {
            #pragma unroll
            for (int k = 0; k < 8; ++k) nxt[k] = 0ull;
        }
        #pragma unroll
        for (int k = 0; k < 8; ++k) {
            int i = b * 8 + k;
            int owner = i >> 6, bit = i & 63;
            int pack = (int)((remv >> bit) & 1ull) | ((int)((vw >> bit) & 1ull) << 1);
            pack = __shfl(pack, owner);
            if ((pack & 2) && !(pack & 1)) {    // valid && !suppressed
                remv |= cur[k];
                if (lane == owner) kb |= (1ull << bit);
            }
        }
        #pragma unroll
        for (int k = 0; k < 8; ++k) cur[k] = nxt[k];
    }
    if (lane < 32) keepmask[m * 32 + lane] = kb;
}

// ---------------- K6: gather + write final output ----------------
__global__ void k6_out(const float* __restrict__ pred, const u64* __restrict__ sel,
                       const u64* __restrict__ keepmask, float4* __restrict__ out) {
    int gid = blockIdx.x * 256 + threadIdx.x;   // NIMG*TOPK*4 float4-chunks
    int c4 = gid & 3;
    int r  = (gid >> 2) & (TOPK - 1);
    int m  = gid >> 13;
    float4 o = make_float4(0.f, 0.f, 0.f, 0.f);
    if ((keepmask[m * 32 + (r >> 6)] >> (r & 63)) & 1ull) {
        u64 key = sel[(size_t)m * TOPK + r];
        unsigned idx = 0xFFFFFFFFu - (unsigned)(key & 0xFFFFFFFFull);
        const float4* rv = reinterpret_cast<const float4*>(pred + ((size_t)m * NA + idx) * 16);
        float4 v = rv[c4];
        if (c4 == 0) {
            float hw = __fmul_rn(v.z, 0.5f), hh = __fmul_rn(v.w, 0.5f);
            o = make_float4(__fsub_rn(v.x, hw), __fsub_rn(v.y, hh),
                            __fadd_rn(v.x, hw), __fadd_rn(v.y, hh));
        } else if (c4 == 1) {
            o = make_float4(__uint_as_float((unsigned)(key >> 32)), v.y, v.z, v.w);
        } else if (c4 == 2) {
            o = v;
        } else {
            o = make_float4(v.x, v.y, v.z, 0.f);
        }
    }
    out[gid] = o;
}

// ---------------- launch ----------------
extern "C" void kernel_launch(void* const* d_in, const int* in_sizes, int n_in,
                              void* d_out, int out_size, void* d_ws, size_t ws_size,
                              hipStream_t stream) {
    (void)in_sizes; (void)n_in; (void)out_size; (void)ws_size;
    const float* pred = (const float*)d_in[0];
    char* ws = (char*)d_ws;
    // layout (bytes):
    u64*    cand     = (u64*)   (ws + 0);          //  8*100800*8 = 6,451,200
    int*    counts   = (int*)   (ws + 6451200);    //  32 (padded to 64)
    u64*    sel      = (u64*)   (ws + 6451264);    //  8*2048*8   = 131,072
    float4* boxes    = (float4*)(ws + 6582336);    //  8*2048*16  = 262,144
    u64*    maskm    = (u64*)   (ws + 6844480);    //  8*2048*32*8= 4,194,304
    u64*    keepmask = (u64*)   (ws + 11038784);   //  8*32*8     = 2,048
    float4* out      = (float4*)d_out;

    hipLaunchKernelGGL(k0_init,    dim3(1),                  dim3(64),   0, stream, counts);
    hipLaunchKernelGGL(k1_compact, dim3((NA + 255) / 256, NIMG), dim3(256), 0, stream, pred, cand, counts);
    hipLaunchKernelGGL(k2_select,  dim3(NIMG),               dim3(1024), 0, stream, cand, counts, sel);
    hipLaunchKernelGGL(k3_boxes,   dim3((NIMG * TOPK + 255) / 256), dim3(256), 0, stream, pred, sel, boxes);
    hipLaunchKernelGGL(k4_masks,   dim3(64, NIMG),           dim3(1024), 0, stream, boxes, maskm);
    hipLaunchKernelGGL(k5_nms,     dim3(NIMG),               dim3(64),   0, stream, sel, maskm, keepmask);
    hipLaunchKernelGGL(k6_out,     dim3(NIMG * TOPK * 4 / 256), dim3(256), 0, stream, pred, sel, keepmask, out);
}

// Round 2
// 471.310 us; speedup vs baseline: 1.5547x; 1.5547x over previous
//
#include <hip/hip_runtime.h>
#include <stdint.h>

#define NA   100800
#define NIMG 8
#define TOPK 2048
typedef unsigned long long u64;

// comp buffer lives inside cand's per-image stride at slot 65536 (k1 writes < ~20K slots)
#define COMP_OFF 65536

// ---------------- K0: zero counters / histogram ----------------
__global__ void k0_init(int* counts, int* hist, int* pos) {
    int t = threadIdx.x;
    if (t < NIMG) counts[t] = 0;
    if (t < NIMG) pos[t] = 0;
    if (t < NIMG * 64) hist[t] = 0;
}

// ---------------- K1: filter + compact sort keys + 64-bin conf histogram ----------------
// key = (conf_bits << 32) | (0xFFFFFFFF - idx)  -> desc key == (conf desc, idx asc)
__global__ void k1_compact(const float* __restrict__ pred,
                           u64* __restrict__ cand, int* __restrict__ counts,
                           int* __restrict__ hist) {
    int m = blockIdx.y;
    int a = blockIdx.x * 256 + threadIdx.x;
    bool valid = false;
    u64 key = 0;
    if (a < NA) {
        const float* row = pred + ((size_t)m * NA + a) * 16;
        float obj  = row[4];
        float x15  = row[15];
        float conf = __fmul_rn(x15, obj);          // exact same single f32 mul as ref
        if (obj > 0.5f && conf > 0.5f) {
            valid = true;
            unsigned cb = __float_as_uint(conf);
            key = ((u64)cb << 32) | (u64)(0xFFFFFFFFu - (unsigned)a);
            int bin = min(63, (int)((cb - 0x3F000000u) >> 17));
            atomicAdd(&hist[(m << 6) + bin], 1);
        }
    }
    u64 bal = __ballot(valid);
    if (bal == 0ull) return;
    int lane   = threadIdx.x & 63;
    int leader = __ffsll(bal) - 1;
    int total  = __popcll(bal);
    int base   = 0;
    if (lane == leader) base = atomicAdd(&counts[m], total);
    base = __shfl(base, leader);
    if (valid) {
        int rank = __popcll(bal & ((1ull << lane) - 1ull));
        cand[(size_t)m * NA + base + rank] = key;
    }
}

// ---------------- K2a: per-image cutoff bin via shuffle suffix-scan (1 wave/image) ----------------
__global__ void k2a_cutoff(const int* __restrict__ counts, const int* __restrict__ hist,
                           int* __restrict__ cut) {
    int m = blockIdx.x;
    int lane = threadIdx.x;                     // 64 threads
    int h = hist[(m << 6) + lane];
    // inclusive suffix sum: h = sum of hist[lane..63]
    #pragma unroll
    for (int off = 1; off < 64; off <<= 1) {
        int src = lane + off;
        int v = __shfl(h, src < 64 ? src : lane);
        h += (src < 64) ? v : 0;
    }
    int total  = __shfl(h, 0);
    int needed = min(total, TOPK);
    u64 bal = __ballot(h >= needed);            // bit 0 always set (h[0]=total>=needed)
    int cutoff = 63 - __clzll(bal);             // highest bin with suffix >= needed
    if (lane == 0) cut[m] = cutoff;
}

// ---------------- K2b: compact keys with bin >= cutoff ----------------
__global__ void k2b_compact(const u64* __restrict__ cand, const int* __restrict__ counts,
                            const int* __restrict__ cut, u64* __restrict__ comp,
                            int* __restrict__ pos) {
    int m = blockIdx.y;
    int i = blockIdx.x * 256 + threadIdx.x;
    if (i >= counts[m]) return;
    u64 key = cand[(size_t)m * NA + i];
    unsigned cb = (unsigned)(key >> 32);
    int bin = min(63, (int)((cb - 0x3F000000u) >> 17));
    if (bin >= cut[m]) {
        int p = atomicAdd(&pos[m], 1);
        if (p < 4096) comp[(size_t)m * NA + COMP_OFF + p] = key;
    }
}

// ---------------- K2c: single 4096-element bitonic sort desc, emit top-2048 ----------------
__global__ __launch_bounds__(1024) void k2c_sort(const u64* __restrict__ comp,
                                                 const int* __restrict__ pos,
                                                 u64* __restrict__ sel) {
    __shared__ u64 buf[4096];
    int m   = blockIdx.x;
    int tid = threadIdx.x;
    int M = min(pos[m], 4096);
    const u64* c = comp + (size_t)m * NA + COMP_OFF;
    #pragma unroll
    for (int r = 0; r < 4; ++r) {
        int i = tid + r * 1024;
        buf[i] = (i < M) ? c[i] : 0ull;         // 0 sentinel below all real keys
    }
    for (int k = 2; k <= 4096; k <<= 1) {
        for (int j = k >> 1; j > 0; j >>= 1) {
            __syncthreads();
            #pragma unroll
            for (int r = 0; r < 4; ++r) {
                int i = tid + r * 1024;
                int l = i ^ j;
                if (l > i) {
                    u64 A = buf[i], B = buf[l];
                    bool up = ((i & k) == 0);
                    if (up ? (A < B) : (A > B)) { buf[i] = B; buf[l] = A; }
                }
            }
        }
    }
    __syncthreads();
    #pragma unroll
    for (int r = 0; r < 2; ++r) {
        int i = tid + r * 1024;
        sel[(size_t)m * TOPK + i] = buf[i];
    }
}

// ---------------- K3: stage xyxy boxes for selected slots ----------------
__global__ void k3_boxes(const float* __restrict__ pred, const u64* __restrict__ sel,
                         float4* __restrict__ boxes) {
    int gid = blockIdx.x * 256 + threadIdx.x;
    if (gid >= NIMG * TOPK) return;
    int m = gid >> 11;
    u64 key = sel[gid];
    float4 b = make_float4(0.f, 0.f, 0.f, 0.f);
    if (key) {
        unsigned idx = 0xFFFFFFFFu - (unsigned)(key & 0xFFFFFFFFull);
        const float4* rv = reinterpret_cast<const float4*>(pred + ((size_t)m * NA + idx) * 16);
        float4 v = rv[0];                       // [xc, yc, w, h]
        float hw = __fmul_rn(v.z, 0.5f), hh = __fmul_rn(v.w, 0.5f);
        b.x = __fsub_rn(v.x, hw);
        b.y = __fsub_rn(v.y, hh);
        b.z = __fadd_rn(v.x, hw);
        b.w = __fadd_rn(v.y, hh);
    }
    boxes[gid] = b;
}

// ---------------- K4: 2048x2048 suppression bitmask (iou > 0.45) ----------------
__global__ __launch_bounds__(1024) void k4_masks(const float4* __restrict__ boxes,
                                                 u64* __restrict__ maskm) {
    __shared__ float4 bx[TOPK];
    int m   = blockIdx.y;
    int grp = blockIdx.x;                       // 64 groups of 32 rows
    for (int i = threadIdx.x; i < TOPK; i += 1024)
        bx[i] = boxes[(size_t)m * TOPK + i];
    __syncthreads();

    int il = threadIdx.x & 31;
    int w  = threadIdx.x >> 5;
    int i  = grp * 32 + il;
    float4 b1 = bx[i];
    float a1 = __fmul_rn(__fsub_rn(b1.z, b1.x), __fsub_rn(b1.w, b1.y));
    u64 bits = 0ull;
    #pragma unroll 4
    for (int jj = 0; jj < 64; ++jj) {
        float4 b2 = bx[w * 64 + jj];
        float a2 = __fmul_rn(__fsub_rn(b2.z, b2.x), __fsub_rn(b2.w, b2.y));
        float iw = fmaxf(__fsub_rn(fminf(b1.z, b2.z), fmaxf(b1.x, b2.x)), 0.f);
        float ih = fmaxf(__fsub_rn(fminf(b1.w, b2.w), fmaxf(b1.y, b2.y)), 0.f);
        float inter = __fmul_rn(iw, ih);
        float uni   = __fsub_rn(__fadd_rn(a1, a2), inter);   // (a1+a2)-inter, ref order
        float iou   = __fdiv_rn(inter, uni);
        if (iou > 0.45f) bits |= (1ull << jj);
    }
    maskm[((size_t)m * TOPK + i) * 32 + w] = bits;
}

// ---------------- K5: greedy scan, ballot-based (1 wave / image) ----------------
// Uses IoU-matrix symmetry: bit j of dval (lane l's diagonal word) == "row j suppresses row l".
__global__ void k5_nms(const u64* __restrict__ sel, const u64* __restrict__ maskm,
                       u64* __restrict__ keepmask) {
    int m = blockIdx.x;
    int lane = threadIdx.x;                     // 64 threads = 1 wave
    const u64* mbase = maskm + (size_t)m * TOPK * 32;

    u64 rw = 0ull;                              // distributed remv: lane w (<32) owns word w
    // prefetch block 0
    u64 dval = mbase[(size_t)lane * 32 + 0];            // row lane, word 0 (diag block 0)
    u64 sval = sel[(size_t)m * TOPK + lane];

    for (int blk = 0; blk < 32; ++blk) {
        u64 dnxt = 0ull, snxt = 0ull;
        if (blk < 31) {
            int r = (blk + 1) * 64 + lane;
            dnxt = mbase[(size_t)r * 32 + (blk + 1)];   // next diagonal block
            snxt = sel[(size_t)m * TOPK + r];
        }
        u64 remw = __shfl(rw, blk);             // remv word blk, replicated
        int sup = (int)((remw >> lane) & 1ull) | (sval == 0ull ? 1 : 0);
        u64 kb = 0ull;
        u64 upd = 0ull;
        const u64* rowp = mbase + (size_t)(blk * 64) * 32 + (lane & 31);
        #pragma unroll 8
        for (int j = 0; j < 64; ++j) {
            u64 bal = __ballot(sup != 0);
            if (!((bal >> j) & 1ull)) {         // row j kept (wave-uniform)
                kb |= (1ull << j);
                sup |= (int)((dval >> j) & 1ull);
                upd |= rowp[(size_t)j * 32];    // consumed only at block end
            }
        }
        if (lane < 32) rw |= upd;
        if (lane == 0) keepmask[m * 32 + blk] = kb;
        dval = dnxt; sval = snxt;
    }
}

// ---------------- K6: gather + write final output ----------------
__global__ void k6_out(const float* __restrict__ pred, const u64* __restrict__ sel,
                       const u64* __restrict__ keepmask, float4* __restrict__ out) {
    int gid = blockIdx.x * 256 + threadIdx.x;   // NIMG*TOPK*4 float4-chunks
    int c4 = gid & 3;
    int r  = (gid >> 2) & (TOPK - 1);
    int m  = gid >> 13;
    float4 o = make_float4(0.f, 0.f, 0.f, 0.f);
    if ((keepmask[m * 32 + (r >> 6)] >> (r & 63)) & 1ull) {
        u64 key = sel[(size_t)m * TOPK + r];
        unsigned idx = 0xFFFFFFFFu - (unsigned)(key & 0xFFFFFFFFull);
        const float4* rv = reinterpret_cast<const float4*>(pred + ((size_t)m * NA + idx) * 16);
        float4 v = rv[c4];
        if (c4 == 0) {
            float hw = __fmul_rn(v.z, 0.5f), hh = __fmul_rn(v.w, 0.5f);
            o = make_float4(__fsub_rn(v.x, hw), __fsub_rn(v.y, hh),
                            __fadd_rn(v.x, hw), __fadd_rn(v.y, hh));
        } else if (c4 == 1) {
            o = make_float4(__uint_as_float((unsigned)(key >> 32)), v.y, v.z, v.w);
        } else if (c4 == 2) {
            o = v;
        } else {
            o = make_float4(v.x, v.y, v.z, 0.f);
        }
    }
    out[gid] = o;
}

// ---------------- launch ----------------
extern "C" void kernel_launch(void* const* d_in, const int* in_sizes, int n_in,
                              void* d_out, int out_size, void* d_ws, size_t ws_size,
                              hipStream_t stream) {
    (void)in_sizes; (void)n_in; (void)out_size; (void)ws_size;
    const float* pred = (const float*)d_in[0];
    char* ws = (char*)d_ws;
    // layout (bytes):
    u64*    cand     = (u64*)   (ws + 0);          //  8*100800*8 = 6,451,200 (comp embedded @slot 65536)
    int*    counts   = (int*)   (ws + 6451200);    //  32 (padded)
    u64*    sel      = (u64*)   (ws + 6451264);    //  8*2048*8   = 131,072
    float4* boxes    = (float4*)(ws + 6582336);    //  8*2048*16  = 262,144
    u64*    maskm    = (u64*)   (ws + 6844480);    //  8*2048*32*8= 4,194,304
    u64*    keepmask = (u64*)   (ws + 11038784);   //  8*32*8     = 2,048
    int*    hist     = (int*)   (ws + 11040832);   //  8*64*4     = 2,048
    int*    pos      = (int*)   (ws + 11042880);   //  32
    int*    cut      = (int*)   (ws + 11042912);   //  32
    float4* out      = (float4*)d_out;

    hipLaunchKernelGGL(k0_init,     dim3(1),                      dim3(512),  0, stream, counts, hist, pos);
    hipLaunchKernelGGL(k1_compact,  dim3((NA + 255) / 256, NIMG), dim3(256),  0, stream, pred, cand, counts, hist);
    hipLaunchKernelGGL(k2a_cutoff,  dim3(NIMG),                   dim3(64),   0, stream, counts, hist, cut);
    hipLaunchKernelGGL(k2b_compact, dim3((NA + 255) / 256, NIMG), dim3(256),  0, stream, cand, counts, cut, cand, pos);
    hipLaunchKernelGGL(k2c_sort,    dim3(NIMG),                   dim3(1024), 0, stream, cand, pos, sel);
    hipLaunchKernelGGL(k3_boxes,    dim3((NIMG * TOPK + 255) / 256), dim3(256), 0, stream, pred, sel, boxes);
    hipLaunchKernelGGL(k4_masks,    dim3(64, NIMG),               dim3(1024), 0, stream, boxes, maskm);
    hipLaunchKernelGGL(k5_nms,      dim3(NIMG),                   dim3(64),   0, stream, sel, maskm, keepmask);
    hipLaunchKernelGGL(k6_out,      dim3(NIMG * TOPK * 4 / 256),  dim3(256),  0, stream, pred, sel, keepmask, out);
}

// Round 3
// 392.196 us; speedup vs baseline: 1.8683x; 1.2017x over previous
//
#include <hip/hip_runtime.h>
#include <stdint.h>

#define NA   100800
#define NIMG 8
#define TOPK 2048
typedef unsigned long long u64;

// comp buffer lives inside cand's per-image stride at slot 65536 (k1 writes < ~20K slots)
#define COMP_OFF 65536

// ---------------- K0: zero counters / histogram ----------------
__global__ void k0_init(int* counts, int* hist, int* pos) {
    int t = threadIdx.x;
    if (t < NIMG) counts[t] = 0;
    if (t < NIMG) pos[t] = 0;
    if (t < NIMG * 64) hist[t] = 0;
}

// ---------------- K1: filter + compact sort keys + 64-bin conf histogram ----------------
// key = (conf_bits << 32) | (0xFFFFFFFF - idx)  -> desc key == (conf desc, idx asc)
__global__ void k1_compact(const float* __restrict__ pred,
                           u64* __restrict__ cand, int* __restrict__ counts,
                           int* __restrict__ hist) {
    int m = blockIdx.y;
    int a = blockIdx.x * 256 + threadIdx.x;
    bool valid = false;
    u64 key = 0;
    if (a < NA) {
        const float* row = pred + ((size_t)m * NA + a) * 16;
        float obj  = row[4];
        float x15  = row[15];
        float conf = __fmul_rn(x15, obj);          // exact same single f32 mul as ref
        if (obj > 0.5f && conf > 0.5f) {
            valid = true;
            unsigned cb = __float_as_uint(conf);
            key = ((u64)cb << 32) | (u64)(0xFFFFFFFFu - (unsigned)a);
            int bin = min(63, (int)((cb - 0x3F000000u) >> 17));
            atomicAdd(&hist[(m << 6) + bin], 1);
        }
    }
    u64 bal = __ballot(valid);
    if (bal == 0ull) return;
    int lane   = threadIdx.x & 63;
    int leader = __ffsll(bal) - 1;
    int total  = __popcll(bal);
    int base   = 0;
    if (lane == leader) base = atomicAdd(&counts[m], total);
    base = __shfl(base, leader);
    if (valid) {
        int rank = __popcll(bal & ((1ull << lane) - 1ull));
        cand[(size_t)m * NA + base + rank] = key;
    }
}

// ---------------- K2a: per-image cutoff bin via shuffle suffix-scan (1 wave/image) ----------------
__global__ void k2a_cutoff(const int* __restrict__ counts, const int* __restrict__ hist,
                           int* __restrict__ cut) {
    int m = blockIdx.x;
    int lane = threadIdx.x;                     // 64 threads
    int h = hist[(m << 6) + lane];
    // inclusive suffix sum: h = sum of hist[lane..63]
    #pragma unroll
    for (int off = 1; off < 64; off <<= 1) {
        int src = lane + off;
        int v = __shfl(h, src < 64 ? src : lane);
        h += (src < 64) ? v : 0;
    }
    int total  = __shfl(h, 0);
    int needed = min(total, TOPK);
    u64 bal = __ballot(h >= needed);            // bit 0 always set (h[0]=total>=needed)
    int cutoff = 63 - __clzll(bal);             // highest bin with suffix >= needed
    if (lane == 0) cut[m] = cutoff;
}

// ---------------- K2b: compact keys with bin >= cutoff ----------------
__global__ void k2b_compact(const u64* __restrict__ cand, const int* __restrict__ counts,
                            const int* __restrict__ cut, u64* __restrict__ comp,
                            int* __restrict__ pos) {
    int m = blockIdx.y;
    int i = blockIdx.x * 256 + threadIdx.x;
    if (i >= counts[m]) return;
    u64 key = cand[(size_t)m * NA + i];
    unsigned cb = (unsigned)(key >> 32);
    int bin = min(63, (int)((cb - 0x3F000000u) >> 17));
    if (bin >= cut[m]) {
        int p = atomicAdd(&pos[m], 1);
        if (p < 4096) comp[(size_t)m * NA + COMP_OFF + p] = key;
    }
}

// ---------------- K2c: single 4096-element bitonic sort desc, emit top-2048 ----------------
// strided ownership: thread owns items tid, tid+1024, tid+2048, tid+3072.
// partner thread for exchange dist j<1024 is tid^j -> same wave when j<64:
// those rounds are wave-synchronous (lockstep), barrier only for j>=32.
__global__ __launch_bounds__(1024) void k2c_sort(const u64* __restrict__ comp,
                                                 const int* __restrict__ pos,
                                                 u64* __restrict__ sel) {
    __shared__ u64 buf[4096];
    int m   = blockIdx.x;
    int tid = threadIdx.x;
    int M = min(pos[m], 4096);
    const u64* c = comp + (size_t)m * NA + COMP_OFF;
    #pragma unroll
    for (int r = 0; r < 4; ++r) {
        int i = tid + r * 1024;
        buf[i] = (i < M) ? c[i] : 0ull;         // 0 sentinel below all real keys
    }
    __syncthreads();
    for (int k = 2; k <= 4096; k <<= 1) {
        for (int j = k >> 1; j > 0; j >>= 1) {
            if (j >= 32) __syncthreads();
            #pragma unroll
            for (int r = 0; r < 4; ++r) {
                int i = tid + r * 1024;
                int l = i ^ j;
                if (l > i) {
                    u64 A = buf[i], B = buf[l];
                    bool up = ((i & k) == 0);
                    if (up ? (A < B) : (A > B)) { buf[i] = B; buf[l] = A; }
                }
            }
        }
    }
    __syncthreads();
    #pragma unroll
    for (int r = 0; r < 2; ++r) {
        int i = tid + r * 1024;
        sel[(size_t)m * TOPK + i] = buf[i];
    }
}

// ---------------- K3: stage xyxy boxes for selected slots ----------------
__global__ void k3_boxes(const float* __restrict__ pred, const u64* __restrict__ sel,
                         float4* __restrict__ boxes) {
    int gid = blockIdx.x * 256 + threadIdx.x;
    if (gid >= NIMG * TOPK) return;
    int m = gid >> 11;
    u64 key = sel[gid];
    float4 b = make_float4(0.f, 0.f, 0.f, 0.f);
    if (key) {
        unsigned idx = 0xFFFFFFFFu - (unsigned)(key & 0xFFFFFFFFull);
        const float4* rv = reinterpret_cast<const float4*>(pred + ((size_t)m * NA + idx) * 16);
        float4 v = rv[0];                       // [xc, yc, w, h]
        float hw = __fmul_rn(v.z, 0.5f), hh = __fmul_rn(v.w, 0.5f);
        b.x = __fsub_rn(v.x, hw);
        b.y = __fsub_rn(v.y, hh);
        b.z = __fadd_rn(v.x, hw);
        b.w = __fadd_rn(v.y, hh);
    }
    boxes[gid] = b;
}

// ---------------- K4: 2048x2048 suppression bitmask (iou > 0.45) ----------------
__global__ __launch_bounds__(1024) void k4_masks(const float4* __restrict__ boxes,
                                                 u64* __restrict__ maskm) {
    __shared__ float4 bx[TOPK];
    int m   = blockIdx.y;
    int grp = blockIdx.x;                       // 64 groups of 32 rows
    for (int i = threadIdx.x; i < TOPK; i += 1024)
        bx[i] = boxes[(size_t)m * TOPK + i];
    __syncthreads();

    int il = threadIdx.x & 31;
    int w  = threadIdx.x >> 5;
    int i  = grp * 32 + il;
    float4 b1 = bx[i];
    float a1 = __fmul_rn(__fsub_rn(b1.z, b1.x), __fsub_rn(b1.w, b1.y));
    u64 bits = 0ull;
    #pragma unroll 4
    for (int jj = 0; jj < 64; ++jj) {
        float4 b2 = bx[w * 64 + jj];
        float a2 = __fmul_rn(__fsub_rn(b2.z, b2.x), __fsub_rn(b2.w, b2.y));
        float iw = fmaxf(__fsub_rn(fminf(b1.z, b2.z), fmaxf(b1.x, b2.x)), 0.f);
        float ih = fmaxf(__fsub_rn(fminf(b1.w, b2.w), fmaxf(b1.y, b2.y)), 0.f);
        float inter = __fmul_rn(iw, ih);
        float uni   = __fsub_rn(__fadd_rn(a1, a2), inter);   // (a1+a2)-inter, ref order
        float iou   = __fdiv_rn(inter, uni);
        if (iou > 0.45f) bits |= (1ull << jj);
    }
    maskm[((size_t)m * TOPK + i) * 32 + w] = bits;
}

// ---------------- K5: greedy scan, lazy per-block gather (1 wave / image) ----------------
// Per block: external suppression word = OR of mask[i][blk] over all kept i in
// previous blocks, gathered in parallel (lane l handles rows pb*64+l), then
// 6-step shfl_xor OR-reduce. Within-block: one ballot per KEPT row, using IoU
// symmetry (bit j of own diagonal word == "row j suppresses me").
__global__ void k5_nms(const u64* __restrict__ sel, const u64* __restrict__ maskm,
                       u64* __restrict__ keepmask) {
    __shared__ u64 kws[32];                     // keep-word per processed block
    int m = blockIdx.x;
    int lane = threadIdx.x;                     // 64 threads = 1 wave
    const u64* mbase = maskm + (size_t)m * TOPK * 32;

    u64 dval = mbase[(size_t)lane * 32 + 0];    // row lane, diagonal word of block 0
    u64 sval = sel[(size_t)m * TOPK + lane];

    for (int blk = 0; blk < 32; ++blk) {
        u64 dnxt = 0ull, snxt = 0ull;
        if (blk < 31) {
            int r = (blk + 1) * 64 + lane;
            dnxt = mbase[(size_t)r * 32 + (blk + 1)];
            snxt = sel[(size_t)m * TOPK + r];
        }
        // lazy gather of external suppression for this block (parallel across lanes)
        u64 acc = 0ull;
        #pragma unroll 4
        for (int pb = 0; pb < blk; ++pb) {
            u64 kw = kws[pb];                   // uniform LDS broadcast
            if ((kw >> lane) & 1ull)
                acc |= mbase[(size_t)(pb * 64 + lane) * 32 + blk];
        }
        #pragma unroll
        for (int off = 1; off < 64; off <<= 1)
            acc |= __shfl_xor(acc, off);        // wave-OR: acc now uniform remv word
        u64 validw = __ballot(sval != 0ull);
        int sup = (int)((acc >> lane) & 1ull) | (int)(((~validw) >> lane) & 1ull);
        u64 kb = 0ull;
        u64 bal = __ballot(sup == 0);
        while (bal) {
            int j = __ffsll((long long)bal) - 1;
            kb |= (1ull << j);
            sup |= (int)((dval >> j) & 1ull);   // symmetry: row j suppresses lane?
            u64 low = (j < 63) ? ((2ull << j) - 1ull) : ~0ull;
            bal = __ballot(sup == 0) & ~low;    // low-mask guards NaN self-IoU
        }
        if (lane == 0) {
            kws[blk] = kb;
            keepmask[m * 32 + blk] = kb;
        }
        __syncthreads();
        dval = dnxt; sval = snxt;
    }
}

// ---------------- K6: gather + write final output ----------------
__global__ void k6_out(const float* __restrict__ pred, const u64* __restrict__ sel,
                       const u64* __restrict__ keepmask, float4* __restrict__ out) {
    int gid = blockIdx.x * 256 + threadIdx.x;   // NIMG*TOPK*4 float4-chunks
    int c4 = gid & 3;
    int r  = (gid >> 2) & (TOPK - 1);
    int m  = gid >> 13;
    float4 o = make_float4(0.f, 0.f, 0.f, 0.f);
    if ((keepmask[m * 32 + (r >> 6)] >> (r & 63)) & 1ull) {
        u64 key = sel[(size_t)m * TOPK + r];
        unsigned idx = 0xFFFFFFFFu - (unsigned)(key & 0xFFFFFFFFull);
        const float4* rv = reinterpret_cast<const float4*>(pred + ((size_t)m * NA + idx) * 16);
        float4 v = rv[c4];
        if (c4 == 0) {
            float hw = __fmul_rn(v.z, 0.5f), hh = __fmul_rn(v.w, 0.5f);
            o = make_float4(__fsub_rn(v.x, hw), __fsub_rn(v.y, hh),
                            __fadd_rn(v.x, hw), __fadd_rn(v.y, hh));
        } else if (c4 == 1) {
            o = make_float4(__uint_as_float((unsigned)(key >> 32)), v.y, v.z, v.w);
        } else if (c4 == 2) {
            o = v;
        } else {
            o = make_float4(v.x, v.y, v.z, 0.f);
        }
    }
    out[gid] = o;
}

// ---------------- launch ----------------
extern "C" void kernel_launch(void* const* d_in, const int* in_sizes, int n_in,
                              void* d_out, int out_size, void* d_ws, size_t ws_size,
                              hipStream_t stream) {
    (void)in_sizes; (void)n_in; (void)out_size; (void)ws_size;
    const float* pred = (const float*)d_in[0];
    char* ws = (char*)d_ws;
    // layout (bytes):
    u64*    cand     = (u64*)   (ws + 0);          //  8*100800*8 = 6,451,200 (comp embedded @slot 65536)
    int*    counts   = (int*)   (ws + 6451200);    //  32 (padded)
    u64*    sel      = (u64*)   (ws + 6451264);    //  8*2048*8   = 131,072
    float4* boxes    = (float4*)(ws + 6582336);    //  8*2048*16  = 262,144
    u64*    maskm    = (u64*)   (ws + 6844480);    //  8*2048*32*8= 4,194,304
    u64*    keepmask = (u64*)   (ws + 11038784);   //  8*32*8     = 2,048
    int*    hist     = (int*)   (ws + 11040832);   //  8*64*4     = 2,048
    int*    pos      = (int*)   (ws + 11042880);   //  32
    int*    cut      = (int*)   (ws + 11042912);   //  32
    float4* out      = (float4*)d_out;

    hipLaunchKernelGGL(k0_init,     dim3(1),                      dim3(512),  0, stream, counts, hist, pos);
    hipLaunchKernelGGL(k1_compact,  dim3((NA + 255) / 256, NIMG), dim3(256),  0, stream, pred, cand, counts, hist);
    hipLaunchKernelGGL(k2a_cutoff,  dim3(NIMG),                   dim3(64),   0, stream, counts, hist, cut);
    hipLaunchKernelGGL(k2b_compact, dim3((NA + 255) / 256, NIMG), dim3(256),  0, stream, cand, counts, cut, cand, pos);
    hipLaunchKernelGGL(k2c_sort,    dim3(NIMG),                   dim3(1024), 0, stream, cand, pos, sel);
    hipLaunchKernelGGL(k3_boxes,    dim3((NIMG * TOPK + 255) / 256), dim3(256), 0, stream, pred, sel, boxes);
    hipLaunchKernelGGL(k4_masks,    dim3(64, NIMG),               dim3(1024), 0, stream, boxes, maskm);
    hipLaunchKernelGGL(k5_nms,      dim3(NIMG),                   dim3(64),   0, stream, sel, maskm, keepmask);
    hipLaunchKernelGGL(k6_out,      dim3(NIMG * TOPK * 4 / 256),  dim3(256),  0, stream, pred, sel, keepmask, out);
}

// Round 5
// 244.003 us; speedup vs baseline: 3.0030x; 1.6073x over previous
//
#include <hip/hip_runtime.h>
#include <stdint.h>

#define NA    100800
#define NIMG  8
#define TOPK  2048
#define NBLK1 99              // ceil(NA / 1024)
typedef unsigned long long u64;

// ---------------- K1: coalesced scan -> dense conf-bits + per-block LDS hist ----------------
// Row = 64 B = 4 float4s; we need quarter#1 (obj at .x) and quarter#3 (x15 at .w):
// exactly the ODD float4 indices. Thread t loads f4[2t+1] and f4[2t+513] (dense),
// __shfl_xor(1) pairs obj with x15. Even lane finalizes rows r and r+128.
__global__ __launch_bounds__(256) void k1_scan(const float* __restrict__ pred,
                                               unsigned* __restrict__ cand32,
                                               int* __restrict__ hist_blocks) {
    __shared__ int lhist[64];
    int t = threadIdx.x;
    int m = blockIdx.y;
    if (t < 64) lhist[t] = 0;
    __syncthreads();
    const float4* p4 = reinterpret_cast<const float4*>(pred + (size_t)m * NA * 16);
    int row0blk = blockIdx.x * 1024;
    for (int pass = 0; pass < 4; ++pass) {
        int row0 = row0blk + pass * 256;
        int i1 = row0 * 4 + 2 * t + 1;
        int i2 = i1 + 512;
        float4 A = make_float4(0.f, 0.f, 0.f, 0.f);
        float4 B = make_float4(0.f, 0.f, 0.f, 0.f);
        if ((i1 >> 2) < NA) A = p4[i1];
        if ((i2 >> 2) < NA) B = p4[i2];
        float aw = __shfl_xor(A.w, 1);          // x15 of row rA (valid on even lanes)
        float bw = __shfl_xor(B.w, 1);          // x15 of row rB
        if (!(t & 1)) {
            int rA = row0 + (t >> 1);
            int rB = rA + 128;
            {
                float obj = A.x, x15 = aw;
                if (rA < NA) {
                    float conf = __fmul_rn(x15, obj);   // exact ref op
                    unsigned cb = 0u;
                    if (obj > 0.5f && conf > 0.5f) {
                        cb = __float_as_uint(conf);
                        atomicAdd(&lhist[min(63, (int)((cb - 0x3F000000u) >> 17))], 1);
                    }
                    cand32[(size_t)m * NA + rA] = cb;
                }
            }
            {
                float obj = B.x, x15 = bw;
                if (rB < NA) {
                    float conf = __fmul_rn(x15, obj);
                    unsigned cb = 0u;
                    if (obj > 0.5f && conf > 0.5f) {
                        cb = __float_as_uint(conf);
                        atomicAdd(&lhist[min(63, (int)((cb - 0x3F000000u) >> 17))], 1);
                    }
                    cand32[(size_t)m * NA + rB] = cb;
                }
            }
        }
    }
    __syncthreads();
    if (t < 64) hist_blocks[((size_t)m * NBLK1 + blockIdx.x) * 64 + t] = lhist[t];
}

// ---------------- K1r: sum per-block hists (coalesced; no atomics) ----------------
__global__ void k1_reduce(const int* __restrict__ hist_blocks, int* __restrict__ hist) {
    int m = blockIdx.x;       // 8 blocks
    int bin = threadIdx.x;    // 64 threads: wave reads 64 consecutive ints per b
    int s = 0;
    #pragma unroll 4
    for (int b = 0; b < NBLK1; ++b)
        s += hist_blocks[((size_t)m * NBLK1 + b) * 64 + bin];
    hist[m * 64 + bin] = s;
}

// ---------------- K2a: cutoff bin via shuffle suffix-scan (1 wave/image) ----------------
__global__ void k2a_cutoff(const int* __restrict__ hist, int* __restrict__ cut,
                           int* __restrict__ pos) {
    int m = blockIdx.x;
    int lane = threadIdx.x;                     // 64 threads
    int h = hist[(m << 6) + lane];
    #pragma unroll
    for (int off = 1; off < 64; off <<= 1) {    // inclusive suffix sum
        int src = lane + off;
        int v = __shfl(h, src < 64 ? src : lane);
        h += (src < 64) ? v : 0;
    }
    int total  = __shfl(h, 0);
    int needed = min(total, TOPK);
    u64 bal = __ballot(h >= needed);
    int cutoff = 63 - __clzll(bal);             // highest bin with suffix >= needed
    if (lane == 0) { cut[m] = cutoff; pos[m] = 0; }
}

// ---------------- K2b: compact bin>=cutoff; ONE atomic per 1024-thread block ----------------
__global__ __launch_bounds__(1024) void k2b_compact(const unsigned* __restrict__ cand32,
                                                    const int* __restrict__ cut,
                                                    u64* __restrict__ comp,
                                                    int* __restrict__ pos) {
    __shared__ int wbase[16];
    __shared__ int sbase;
    int m = blockIdx.y;
    int i = blockIdx.x * 1024 + threadIdx.x;
    int lane = threadIdx.x & 63, wid = threadIdx.x >> 6;
    unsigned cb = (i < NA) ? cand32[(size_t)m * NA + i] : 0u;
    int c = cut[m];
    bool keep = false;
    if (cb) keep = min(63, (int)((cb - 0x3F000000u) >> 17)) >= c;
    u64 bal = __ballot(keep);
    int cnt = __popcll(bal);
    if (lane == 0) wbase[wid] = cnt;
    __syncthreads();
    if (threadIdx.x == 0) {
        int s = 0;
        #pragma unroll
        for (int w = 0; w < 16; ++w) { int v = wbase[w]; wbase[w] = s; s += v; }
        sbase = s ? atomicAdd(&pos[m], s) : 0;
    }
    __syncthreads();
    if (keep) {
        int p = sbase + wbase[wid] + (int)__popcll(bal & ((1ull << lane) - 1ull));
        if (p < 4096)
            comp[(size_t)m * 4096 + p] = ((u64)cb << 32) | (u64)(0xFFFFFFFFu - (unsigned)i);
    }
}

// ---------------- K2c: single 4096 bitonic sort desc, emit top-2048 ----------------
// strided ownership: thread owns {t, t+1024, t+2048, t+3072}; partner for dist j
// is thread t^j. SAFETY: at round j, buf[i^j] was written in round 2j by thread
// t^j or t^(j|2j) -> same-wave only if (j|2j) < 64, i.e. j < 32. Barrier at j>=32.
__global__ __launch_bounds__(1024) void k2c_sort(const u64* __restrict__ comp,
                                                 const int* __restrict__ pos,
                                                 u64* __restrict__ sel) {
    __shared__ u64 buf[4096];
    int m   = blockIdx.x;
    int tid = threadIdx.x;
    int M = min(pos[m], 4096);
    const u64* c = comp + (size_t)m * 4096;
    #pragma unroll
    for (int r = 0; r < 4; ++r) {
        int i = tid + r * 1024;
        buf[i] = (i < M) ? c[i] : 0ull;         // 0 sentinel below all real keys
    }
    __syncthreads();
    for (int k = 2; k <= 4096; k <<= 1) {
        for (int j = k >> 1; j > 0; j >>= 1) {
            if (j >= 32) __syncthreads();
            #pragma unroll
            for (int r = 0; r < 4; ++r) {
                int i = tid + r * 1024;
                int l = i ^ j;
                if (l > i) {
                    u64 A = buf[i], B = buf[l];
                    bool up = ((i & k) == 0);
                    if (up ? (A < B) : (A > B)) { buf[i] = B; buf[l] = A; }
                }
            }
        }
    }
    __syncthreads();
    #pragma unroll
    for (int r = 0; r < 2; ++r) {
        int i = tid + r * 1024;
        sel[(size_t)m * TOPK + i] = buf[i];
    }
}

// ---------------- K3: stage xyxy boxes for selected slots ----------------
__global__ void k3_boxes(const float* __restrict__ pred, const u64* __restrict__ sel,
                         float4* __restrict__ boxes) {
    int gid = blockIdx.x * 256 + threadIdx.x;
    if (gid >= NIMG * TOPK) return;
    int m = gid >> 11;
    u64 key = sel[gid];
    float4 b = make_float4(0.f, 0.f, 0.f, 0.f);
    if (key) {
        unsigned idx = 0xFFFFFFFFu - (unsigned)(key & 0xFFFFFFFFull);
        const float4* rv = reinterpret_cast<const float4*>(pred + ((size_t)m * NA + idx) * 16);
        float4 v = rv[0];                       // [xc, yc, w, h]
        float hw = __fmul_rn(v.z, 0.5f), hh = __fmul_rn(v.w, 0.5f);
        b.x = __fsub_rn(v.x, hw);
        b.y = __fsub_rn(v.y, hh);
        b.z = __fadd_rn(v.x, hw);
        b.w = __fadd_rn(v.y, hh);
    }
    boxes[gid] = b;
}

// ---------------- K4: 2048x2048 suppression bitmask (iou > 0.45) ----------------
__global__ __launch_bounds__(1024) void k4_masks(const float4* __restrict__ boxes,
                                                 u64* __restrict__ maskm) {
    __shared__ float4 bx[TOPK];
    int m   = blockIdx.y;
    int grp = blockIdx.x;                       // 64 groups of 32 rows
    for (int i = threadIdx.x; i < TOPK; i += 1024)
        bx[i] = boxes[(size_t)m * TOPK + i];
    __syncthreads();

    int il = threadIdx.x & 31;
    int w  = threadIdx.x >> 5;
    int i  = grp * 32 + il;
    float4 b1 = bx[i];
    float a1 = __fmul_rn(__fsub_rn(b1.z, b1.x), __fsub_rn(b1.w, b1.y));
    u64 bits = 0ull;
    #pragma unroll 4
    for (int jj = 0; jj < 64; ++jj) {
        float4 b2 = bx[w * 64 + jj];
        float a2 = __fmul_rn(__fsub_rn(b2.z, b2.x), __fsub_rn(b2.w, b2.y));
        float iw = fmaxf(__fsub_rn(fminf(b1.z, b2.z), fmaxf(b1.x, b2.x)), 0.f);
        float ih = fmaxf(__fsub_rn(fminf(b1.w, b2.w), fmaxf(b1.y, b2.y)), 0.f);
        float inter = __fmul_rn(iw, ih);
        float uni   = __fsub_rn(__fadd_rn(a1, a2), inter);   // (a1+a2)-inter, ref order
        float iou   = __fdiv_rn(inter, uni);
        if (iou > 0.45f) bits |= (1ull << jj);
    }
    maskm[((size_t)m * TOPK + i) * 32 + w] = bits;
}

// ---------------- K5: greedy scan, lazy per-block gather (1 wave / image) ----------------
__global__ void k5_nms(const u64* __restrict__ sel, const u64* __restrict__ maskm,
                       u64* __restrict__ keepmask) {
    __shared__ u64 kws[32];                     // keep-word per processed block
    int m = blockIdx.x;
    int lane = threadIdx.x;                     // 64 threads = 1 wave
    const u64* mbase = maskm + (size_t)m * TOPK * 32;

    u64 dval = mbase[(size_t)lane * 32 + 0];    // row lane, diagonal word of block 0
    u64 sval = sel[(size_t)m * TOPK + lane];

    for (int blk = 0; blk < 32; ++blk) {
        u64 dnxt = 0ull, snxt = 0ull;
        if (blk < 31) {
            int r = (blk + 1) * 64 + lane;
            dnxt = mbase[(size_t)r * 32 + (blk + 1)];
            snxt = sel[(size_t)m * TOPK + r];
        }
        // lazy gather of external suppression for this block (parallel across lanes)
        u64 acc = 0ull;
        #pragma unroll 4
        for (int pb = 0; pb < blk; ++pb) {
            u64 kw = kws[pb];                   // uniform LDS broadcast
            if ((kw >> lane) & 1ull)
                acc |= mbase[(size_t)(pb * 64 + lane) * 32 + blk];
        }
        #pragma unroll
        for (int off = 1; off < 64; off <<= 1)
            acc |= __shfl_xor(acc, off);        // wave-OR: acc now uniform remv word
        u64 validw = __ballot(sval != 0ull);
        int sup = (int)((acc >> lane) & 1ull) | (int)(((~validw) >> lane) & 1ull);
        u64 kb = 0ull;
        u64 bal = __ballot(sup == 0);
        while (bal) {
            int j = __ffsll((long long)bal) - 1;
            kb |= (1ull << j);
            sup |= (int)((dval >> j) & 1ull);   // symmetry: row j suppresses lane?
            u64 low = (j < 63) ? ((2ull << j) - 1ull) : ~0ull;
            bal = __ballot(sup == 0) & ~low;    // low-mask guards NaN self-IoU
        }
        if (lane == 0) {
            kws[blk] = kb;
            keepmask[m * 32 + blk] = kb;
        }
        __syncthreads();
        dval = dnxt; sval = snxt;
    }
}

// ---------------- K6: gather + write final output ----------------
__global__ void k6_out(const float* __restrict__ pred, const u64* __restrict__ sel,
                       const u64* __restrict__ keepmask, float4* __restrict__ out) {
    int gid = blockIdx.x * 256 + threadIdx.x;   // NIMG*TOPK*4 float4-chunks
    int c4 = gid & 3;
    int r  = (gid >> 2) & (TOPK - 1);
    int m  = gid >> 13;
    float4 o = make_float4(0.f, 0.f, 0.f, 0.f);
    if ((keepmask[m * 32 + (r >> 6)] >> (r & 63)) & 1ull) {
        u64 key = sel[(size_t)m * TOPK + r];
        unsigned idx = 0xFFFFFFFFu - (unsigned)(key & 0xFFFFFFFFull);
        const float4* rv = reinterpret_cast<const float4*>(pred + ((size_t)m * NA + idx) * 16);
        float4 v = rv[c4];
        if (c4 == 0) {
            float hw = __fmul_rn(v.z, 0.5f), hh = __fmul_rn(v.w, 0.5f);
            o = make_float4(__fsub_rn(v.x, hw), __fsub_rn(v.y, hh),
                            __fadd_rn(v.x, hw), __fadd_rn(v.y, hh));
        } else if (c4 == 1) {
            o = make_float4(__uint_as_float((unsigned)(key >> 32)), v.y, v.z, v.w);
        } else if (c4 == 2) {
            o = v;
        } else {
            o = make_float4(v.x, v.y, v.z, 0.f);
        }
    }
    out[gid] = o;
}

// ---------------- launch ----------------
extern "C" void kernel_launch(void* const* d_in, const int* in_sizes, int n_in,
                              void* d_out, int out_size, void* d_ws, size_t ws_size,
                              hipStream_t stream) {
    (void)in_sizes; (void)n_in; (void)out_size; (void)ws_size;
    const float* pred = (const float*)d_in[0];
    char* ws = (char*)d_ws;
    // layout (bytes):
    unsigned* cand32   = (unsigned*)(ws + 0);          // 8*100800*4 = 3,225,600
    u64*      comp     = (u64*)     (ws + 3225600);    // 8*4096*8   =   262,144
    u64*      sel      = (u64*)     (ws + 3487744);    // 8*2048*8   =   131,072
    float4*   boxes    = (float4*)  (ws + 3618816);    // 8*2048*16  =   262,144
    u64*      maskm    = (u64*)     (ws + 3880960);    // 8*2048*32*8= 4,194,304
    u64*      keepmask = (u64*)     (ws + 8075264);    // 8*32*8     =     2,048
    int*      histb    = (int*)     (ws + 8077312);    // 8*99*64*4  =   202,752
    int*      hist     = (int*)     (ws + 8280064);    // 8*64*4     =     2,048
    int*      pos      = (int*)     (ws + 8282112);    // 32
    int*      cut      = (int*)     (ws + 8282144);    // 32
    float4*   out      = (float4*)d_out;

    hipLaunchKernelGGL(k1_scan,    dim3(NBLK1, NIMG),            dim3(256),  0, stream, pred, cand32, histb);
    hipLaunchKernelGGL(k1_reduce,  dim3(NIMG),                   dim3(64),   0, stream, histb, hist);
    hipLaunchKernelGGL(k2a_cutoff, dim3(NIMG),                   dim3(64),   0, stream, hist, cut, pos);
    hipLaunchKernelGGL(k2b_compact,dim3(NBLK1, NIMG),            dim3(1024), 0, stream, cand32, cut, comp, pos);
    hipLaunchKernelGGL(k2c_sort,   dim3(NIMG),                   dim3(1024), 0, stream, comp, pos, sel);
    hipLaunchKernelGGL(k3_boxes,   dim3((NIMG * TOPK + 255) / 256), dim3(256), 0, stream, pred, sel, boxes);
    hipLaunchKernelGGL(k4_masks,   dim3(64, NIMG),               dim3(1024), 0, stream, boxes, maskm);
    hipLaunchKernelGGL(k5_nms,     dim3(NIMG),                   dim3(64),   0, stream, sel, maskm, keepmask);
    hipLaunchKernelGGL(k6_out,     dim3(NIMG * TOPK * 4 / 256),  dim3(256),  0, stream, pred, sel, keepmask, out);
}

// Round 6
// 167.984 us; speedup vs baseline: 4.3619x; 1.4525x over previous
//
#include <hip/hip_runtime.h>
#include <stdint.h>

#define NA    100800
#define NIMG  8
#define TOPK  2048
#define NBLK1 99              // ceil(NA / 1024)
typedef unsigned long long u64;

// ---------------- K1: coalesced scan -> dense conf-bits + per-block LDS hist ----------------
// Row = 64 B = 4 float4s; we need quarter#1 (obj at .x) and quarter#3 (x15 at .w):
// exactly the ODD float4 indices. Thread t loads f4[2t+1] and f4[2t+513] (dense),
// __shfl_xor(1) pairs obj with x15. Even lane finalizes rows r and r+128.
__global__ __launch_bounds__(256) void k1_scan(const float* __restrict__ pred,
                                               unsigned* __restrict__ cand32,
                                               int* __restrict__ hist_blocks) {
    __shared__ int lhist[64];
    int t = threadIdx.x;
    int m = blockIdx.y;
    if (t < 64) lhist[t] = 0;
    __syncthreads();
    const float4* p4 = reinterpret_cast<const float4*>(pred + (size_t)m * NA * 16);
    int row0blk = blockIdx.x * 1024;
    for (int pass = 0; pass < 4; ++pass) {
        int row0 = row0blk + pass * 256;
        int i1 = row0 * 4 + 2 * t + 1;
        int i2 = i1 + 512;
        float4 A = make_float4(0.f, 0.f, 0.f, 0.f);
        float4 B = make_float4(0.f, 0.f, 0.f, 0.f);
        if ((i1 >> 2) < NA) A = p4[i1];
        if ((i2 >> 2) < NA) B = p4[i2];
        float aw = __shfl_xor(A.w, 1);          // x15 of row rA (valid on even lanes)
        float bw = __shfl_xor(B.w, 1);          // x15 of row rB
        if (!(t & 1)) {
            int rA = row0 + (t >> 1);
            int rB = rA + 128;
            {
                float obj = A.x, x15 = aw;
                if (rA < NA) {
                    float conf = __fmul_rn(x15, obj);   // exact ref op
                    unsigned cb = 0u;
                    if (obj > 0.5f && conf > 0.5f) {
                        cb = __float_as_uint(conf);
                        atomicAdd(&lhist[min(63, (int)((cb - 0x3F000000u) >> 17))], 1);
                    }
                    cand32[(size_t)m * NA + rA] = cb;
                }
            }
            {
                float obj = B.x, x15 = bw;
                if (rB < NA) {
                    float conf = __fmul_rn(x15, obj);
                    unsigned cb = 0u;
                    if (obj > 0.5f && conf > 0.5f) {
                        cb = __float_as_uint(conf);
                        atomicAdd(&lhist[min(63, (int)((cb - 0x3F000000u) >> 17))], 1);
                    }
                    cand32[(size_t)m * NA + rB] = cb;
                }
            }
        }
    }
    __syncthreads();
    if (t < 64) hist_blocks[((size_t)m * NBLK1 + blockIdx.x) * 64 + t] = lhist[t];
}

// ---------------- K2a: reduce per-block hists + cutoff via suffix-scan (1 wave/image) ----------------
__global__ void k2a_cutoff(const int* __restrict__ hist_blocks, int* __restrict__ cut,
                           int* __restrict__ pos) {
    int m = blockIdx.x;
    int lane = threadIdx.x;                     // 64 threads
    int h = 0;
    #pragma unroll 4
    for (int b = 0; b < NBLK1; ++b)             // coalesced: 64 consecutive ints per b
        h += hist_blocks[((size_t)m * NBLK1 + b) * 64 + lane];
    #pragma unroll
    for (int off = 1; off < 64; off <<= 1) {    // inclusive suffix sum
        int src = lane + off;
        int v = __shfl(h, src < 64 ? src : lane);
        h += (src < 64) ? v : 0;
    }
    int total  = __shfl(h, 0);
    int needed = min(total, TOPK);
    u64 bal = __ballot(h >= needed);
    int cutoff = 63 - __clzll(bal);             // highest bin with suffix >= needed
    if (lane == 0) { cut[m] = cutoff; pos[m] = 0; }
}

// ---------------- K2b: compact bin>=cutoff; ONE atomic per 1024-thread block ----------------
__global__ __launch_bounds__(1024) void k2b_compact(const unsigned* __restrict__ cand32,
                                                    const int* __restrict__ cut,
                                                    u64* __restrict__ comp,
                                                    int* __restrict__ pos) {
    __shared__ int wbase[16];
    __shared__ int sbase;
    int m = blockIdx.y;
    int i = blockIdx.x * 1024 + threadIdx.x;
    int lane = threadIdx.x & 63, wid = threadIdx.x >> 6;
    unsigned cb = (i < NA) ? cand32[(size_t)m * NA + i] : 0u;
    int c = cut[m];
    bool keep = false;
    if (cb) keep = min(63, (int)((cb - 0x3F000000u) >> 17)) >= c;
    u64 bal = __ballot(keep);
    int cnt = __popcll(bal);
    if (lane == 0) wbase[wid] = cnt;
    __syncthreads();
    if (threadIdx.x == 0) {
        int s = 0;
        #pragma unroll
        for (int w = 0; w < 16; ++w) { int v = wbase[w]; wbase[w] = s; s += v; }
        sbase = s ? atomicAdd(&pos[m], s) : 0;
    }
    __syncthreads();
    if (keep) {
        int p = sbase + wbase[wid] + (int)__popcll(bal & ((1ull << lane) - 1ull));
        if (p < 4096)
            comp[(size_t)m * 4096 + p] = ((u64)cb << 32) | (u64)(0xFFFFFFFFu - (unsigned)i);
    }
}

// ---------------- K2c: 4096 bitonic sort desc -> sel + staged xyxy boxes ----------------
// strided ownership: thread owns {t, t+1024, t+2048, t+3072}; partner for dist j
// is thread t^j. SAFETY: at round j, buf[i^j] was written in round 2j by thread
// t^j or t^(j|2j) -> same-wave only if (j|2j) < 64, i.e. j < 32. Barrier at j>=32.
__global__ __launch_bounds__(1024) void k2c_sort(const u64* __restrict__ comp,
                                                 const int* __restrict__ pos,
                                                 const float* __restrict__ pred,
                                                 u64* __restrict__ sel,
                                                 float4* __restrict__ boxes) {
    __shared__ u64 buf[4096];
    int m   = blockIdx.x;
    int tid = threadIdx.x;
    int M = min(pos[m], 4096);
    const u64* c = comp + (size_t)m * 4096;
    #pragma unroll
    for (int r = 0; r < 4; ++r) {
        int i = tid + r * 1024;
        buf[i] = (i < M) ? c[i] : 0ull;         // 0 sentinel below all real keys
    }
    __syncthreads();
    for (int k = 2; k <= 4096; k <<= 1) {
        for (int j = k >> 1; j > 0; j >>= 1) {
            if (j >= 32) __syncthreads();
            #pragma unroll
            for (int r = 0; r < 4; ++r) {
                int i = tid + r * 1024;
                int l = i ^ j;
                if (l > i) {
                    u64 A = buf[i], B = buf[l];
                    bool up = ((i & k) == 0);
                    if (up ? (A < B) : (A > B)) { buf[i] = B; buf[l] = A; }
                }
            }
        }
    }
    __syncthreads();
    #pragma unroll
    for (int r = 0; r < 2; ++r) {
        int i = tid + r * 1024;
        u64 key = buf[i];
        sel[(size_t)m * TOPK + i] = key;
        float4 b = make_float4(0.f, 0.f, 0.f, 0.f);
        if (key) {
            unsigned idx = 0xFFFFFFFFu - (unsigned)(key & 0xFFFFFFFFull);
            const float4* rv = reinterpret_cast<const float4*>(pred + ((size_t)m * NA + idx) * 16);
            float4 v = rv[0];                   // [xc, yc, w, h]
            float hw = __fmul_rn(v.z, 0.5f), hh = __fmul_rn(v.w, 0.5f);
            b.x = __fsub_rn(v.x, hw);
            b.y = __fsub_rn(v.y, hh);
            b.z = __fadd_rn(v.x, hw);
            b.w = __fadd_rn(v.y, hh);
        }
        boxes[(size_t)m * TOPK + i] = b;
    }
}

// ---------------- K4: 2048x2048 suppression bitmask, TRANSPOSED (iou > 0.45) ----------------
// maskT[(m*32 + w)*2048 + row] : word w of row, stored word-major for coalesced
// per-word access in k5.
__global__ __launch_bounds__(1024) void k4_masks(const float4* __restrict__ boxes,
                                                 u64* __restrict__ maskT) {
    __shared__ float4 bx[TOPK];
    int m   = blockIdx.y;
    int grp = blockIdx.x;                       // 64 groups of 32 rows
    for (int i = threadIdx.x; i < TOPK; i += 1024)
        bx[i] = boxes[(size_t)m * TOPK + i];
    __syncthreads();

    int il = threadIdx.x & 31;
    int w  = threadIdx.x >> 5;
    int i  = grp * 32 + il;
    float4 b1 = bx[i];
    float a1 = __fmul_rn(__fsub_rn(b1.z, b1.x), __fsub_rn(b1.w, b1.y));
    u64 bits = 0ull;
    #pragma unroll 4
    for (int jj = 0; jj < 64; ++jj) {
        float4 b2 = bx[w * 64 + jj];
        float a2 = __fmul_rn(__fsub_rn(b2.z, b2.x), __fsub_rn(b2.w, b2.y));
        float iw = fmaxf(__fsub_rn(fminf(b1.z, b2.z), fmaxf(b1.x, b2.x)), 0.f);
        float ih = fmaxf(__fsub_rn(fminf(b1.w, b2.w), fmaxf(b1.y, b2.y)), 0.f);
        float inter = __fmul_rn(iw, ih);
        float uni   = __fsub_rn(__fadd_rn(a1, a2), inter);   // (a1+a2)-inter, ref order
        float iou   = __fdiv_rn(inter, uni);
        if (iou > 0.45f) bits |= (1ull << jj);
    }
    maskT[((size_t)m * 32 + w) * 2048 + i] = bits;
}

// ---------------- K5: greedy scan, incremental remv (1024 thr / image) ----------------
// Wave 0 runs the sequential within-block ballot scan; after each block, 32
// thread-groups (one per word w>blk) OR the kept rows' maskT entries into
// LDS remv[w] via coalesced loads + 5-step shfl_xor reduce.
__global__ __launch_bounds__(1024) void k5_nms(const u64* __restrict__ sel,
                                               const u64* __restrict__ maskT,
                                               u64* __restrict__ keepmask) {
    __shared__ u64 remv[32];
    __shared__ u64 kbshare;
    int m = blockIdx.x;
    int t = threadIdx.x;
    int lane = t & 63;
    const u64* mt = maskT + (size_t)m * 32 * 2048;
    if (t < 32) remv[t] = 0ull;
    u64 dval = 0ull, sval = 0ull;
    if (t < 64) {                               // wave 0: prefetch block 0
        dval = mt[(size_t)0 * 2048 + t];        // word 0, rows 0..63 (coalesced)
        sval = sel[(size_t)m * TOPK + t];
    }
    __syncthreads();
    int w = t >> 5, sub = t & 31;
    for (int blk = 0; blk < 32; ++blk) {
        if (t < 64) {
            // ---- sequential scan of block blk (wave 0 only) ----
            u64 validw = __ballot(sval != 0ull);
            u64 acc = remv[blk];
            int sup = (int)((acc >> lane) & 1ull) | (int)(((~validw) >> lane) & 1ull);
            u64 kb = 0ull;
            u64 bal = __ballot(sup == 0);
            while (bal) {
                int j = __ffsll((long long)bal) - 1;
                kb |= (1ull << j);
                sup |= (int)((dval >> j) & 1ull);   // symmetry: row j suppresses lane?
                u64 low = (j < 63) ? ((2ull << j) - 1ull) : ~0ull;
                bal = __ballot(sup == 0) & ~low;    // low-mask guards NaN self-IoU
            }
            if (lane == 0) {
                kbshare = kb;
                keepmask[m * 32 + blk] = kb;
            }
            if (blk < 31) {                     // prefetch next block (coalesced)
                int r = (blk + 1) * 64 + lane;
                dval = mt[(size_t)(blk + 1) * 2048 + r];
                sval = sel[(size_t)m * TOPK + r];
            }
        }
        __syncthreads();
        // ---- parallel remv update: group w handles word w ----
        if (w > blk) {
            u64 kb = kbshare;
            if (kb) {
                u64 v = 0ull;
                int r0 = blk * 64 + sub;
                if ((kb >> sub) & 1ull)        v  = mt[(size_t)w * 2048 + r0];
                if ((kb >> (sub + 32)) & 1ull) v |= mt[(size_t)w * 2048 + r0 + 32];
                #pragma unroll
                for (int off = 1; off < 32; off <<= 1)
                    v |= __shfl_xor(v, off);    // reduce within 32-lane group
                if (sub == 0) remv[w] |= v;
            }
        }
        __syncthreads();
    }
}

// ---------------- K6: gather + write final output ----------------
__global__ void k6_out(const float* __restrict__ pred, const u64* __restrict__ sel,
                       const u64* __restrict__ keepmask, float4* __restrict__ out) {
    int gid = blockIdx.x * 256 + threadIdx.x;   // NIMG*TOPK*4 float4-chunks
    int c4 = gid & 3;
    int r  = (gid >> 2) & (TOPK - 1);
    int m  = gid >> 13;
    float4 o = make_float4(0.f, 0.f, 0.f, 0.f);
    if ((keepmask[m * 32 + (r >> 6)] >> (r & 63)) & 1ull) {
        u64 key = sel[(size_t)m * TOPK + r];
        unsigned idx = 0xFFFFFFFFu - (unsigned)(key & 0xFFFFFFFFull);
        const float4* rv = reinterpret_cast<const float4*>(pred + ((size_t)m * NA + idx) * 16);
        float4 v = rv[c4];
        if (c4 == 0) {
            float hw = __fmul_rn(v.z, 0.5f), hh = __fmul_rn(v.w, 0.5f);
            o = make_float4(__fsub_rn(v.x, hw), __fsub_rn(v.y, hh),
                            __fadd_rn(v.x, hw), __fadd_rn(v.y, hh));
        } else if (c4 == 1) {
            o = make_float4(__uint_as_float((unsigned)(key >> 32)), v.y, v.z, v.w);
        } else if (c4 == 2) {
            o = v;
        } else {
            o = make_float4(v.x, v.y, v.z, 0.f);
        }
    }
    out[gid] = o;
}

// ---------------- launch ----------------
extern "C" void kernel_launch(void* const* d_in, const int* in_sizes, int n_in,
                              void* d_out, int out_size, void* d_ws, size_t ws_size,
                              hipStream_t stream) {
    (void)in_sizes; (void)n_in; (void)out_size; (void)ws_size;
    const float* pred = (const float*)d_in[0];
    char* ws = (char*)d_ws;
    // layout (bytes):
    unsigned* cand32   = (unsigned*)(ws + 0);          // 8*100800*4 = 3,225,600
    u64*      comp     = (u64*)     (ws + 3225600);    // 8*4096*8   =   262,144
    u64*      sel      = (u64*)     (ws + 3487744);    // 8*2048*8   =   131,072
    float4*   boxes    = (float4*)  (ws + 3618816);    // 8*2048*16  =   262,144
    u64*      maskT    = (u64*)     (ws + 3880960);    // 8*32*2048*8= 4,194,304
    u64*      keepmask = (u64*)     (ws + 8075264);    // 8*32*8     =     2,048
    int*      histb    = (int*)     (ws + 8077312);    // 8*99*64*4  =   202,752
    int*      pos      = (int*)     (ws + 8280064);    // 32
    int*      cut      = (int*)     (ws + 8280096);    // 32
    float4*   out      = (float4*)d_out;

    hipLaunchKernelGGL(k1_scan,    dim3(NBLK1, NIMG),            dim3(256),  0, stream, pred, cand32, histb);
    hipLaunchKernelGGL(k2a_cutoff, dim3(NIMG),                   dim3(64),   0, stream, histb, cut, pos);
    hipLaunchKernelGGL(k2b_compact,dim3(NBLK1, NIMG),            dim3(1024), 0, stream, cand32, cut, comp, pos);
    hipLaunchKernelGGL(k2c_sort,   dim3(NIMG),                   dim3(1024), 0, stream, comp, pos, pred, sel, boxes);
    hipLaunchKernelGGL(k4_masks,   dim3(64, NIMG),               dim3(1024), 0, stream, boxes, maskT);
    hipLaunchKernelGGL(k5_nms,     dim3(NIMG),                   dim3(1024), 0, stream, sel, maskT, keepmask);
    hipLaunchKernelGGL(k6_out,     dim3(NIMG * TOPK * 4 / 256),  dim3(256),  0, stream, pred, sel, keepmask, out);
}

// Round 7
// 159.337 us; speedup vs baseline: 4.5986x; 1.0543x over previous
//
#include <hip/hip_runtime.h>
#include <stdint.h>

#define NA    100800
#define NIMG  8
#define TOPK  2048
#define NBLK1 99              // ceil(NA / 1024)
typedef unsigned long long u64;

// ---------------- K1: coalesced scan -> dense conf-bits + per-block LDS hist ----------------
// Row = 64 B = 4 float4s; we need quarter#1 (obj at .x) and quarter#3 (x15 at .w):
// exactly the ODD float4 indices. Thread t loads f4[2t+1] and f4[2t+513] (dense),
// __shfl_xor(1) pairs obj with x15. Even lane finalizes rows r and r+128.
__global__ __launch_bounds__(256) void k1_scan(const float* __restrict__ pred,
                                               unsigned* __restrict__ cand32,
                                               int* __restrict__ hist_blocks) {
    __shared__ int lhist[64];
    int t = threadIdx.x;
    int m = blockIdx.y;
    if (t < 64) lhist[t] = 0;
    __syncthreads();
    const float4* p4 = reinterpret_cast<const float4*>(pred + (size_t)m * NA * 16);
    int row0blk = blockIdx.x * 1024;
    for (int pass = 0; pass < 4; ++pass) {
        int row0 = row0blk + pass * 256;
        int i1 = row0 * 4 + 2 * t + 1;
        int i2 = i1 + 512;
        float4 A = make_float4(0.f, 0.f, 0.f, 0.f);
        float4 B = make_float4(0.f, 0.f, 0.f, 0.f);
        if ((i1 >> 2) < NA) A = p4[i1];
        if ((i2 >> 2) < NA) B = p4[i2];
        float aw = __shfl_xor(A.w, 1);          // x15 of row rA (valid on even lanes)
        float bw = __shfl_xor(B.w, 1);          // x15 of row rB
        if (!(t & 1)) {
            int rA = row0 + (t >> 1);
            int rB = rA + 128;
            {
                float obj = A.x, x15 = aw;
                if (rA < NA) {
                    float conf = __fmul_rn(x15, obj);   // exact ref op
                    unsigned cb = 0u;
                    if (obj > 0.5f && conf > 0.5f) {
                        cb = __float_as_uint(conf);
                        atomicAdd(&lhist[min(63, (int)((cb - 0x3F000000u) >> 17))], 1);
                    }
                    cand32[(size_t)m * NA + rA] = cb;
                }
            }
            {
                float obj = B.x, x15 = bw;
                if (rB < NA) {
                    float conf = __fmul_rn(x15, obj);
                    unsigned cb = 0u;
                    if (obj > 0.5f && conf > 0.5f) {
                        cb = __float_as_uint(conf);
                        atomicAdd(&lhist[min(63, (int)((cb - 0x3F000000u) >> 17))], 1);
                    }
                    cand32[(size_t)m * NA + rB] = cb;
                }
            }
        }
    }
    __syncthreads();
    if (t < 64) hist_blocks[((size_t)m * NBLK1 + blockIdx.x) * 64 + t] = lhist[t];
}

// ---------------- K2a: reduce per-block hists + cutoff via suffix-scan (1 wave/image) ----------------
__global__ void k2a_cutoff(const int* __restrict__ hist_blocks, int* __restrict__ cut,
                           int* __restrict__ pos) {
    int m = blockIdx.x;
    int lane = threadIdx.x;                     // 64 threads
    int h = 0;
    #pragma unroll 4
    for (int b = 0; b < NBLK1; ++b)             // coalesced: 64 consecutive ints per b
        h += hist_blocks[((size_t)m * NBLK1 + b) * 64 + lane];
    #pragma unroll
    for (int off = 1; off < 64; off <<= 1) {    // inclusive suffix sum
        int src = lane + off;
        int v = __shfl(h, src < 64 ? src : lane);
        h += (src < 64) ? v : 0;
    }
    int total  = __shfl(h, 0);
    int needed = min(total, TOPK);
    u64 bal = __ballot(h >= needed);
    int cutoff = 63 - __clzll(bal);             // highest bin with suffix >= needed
    if (lane == 0) { cut[m] = cutoff; pos[m] = 0; }
}

// ---------------- K2b: compact bin>=cutoff; ONE atomic per 1024-thread block ----------------
__global__ __launch_bounds__(1024) void k2b_compact(const unsigned* __restrict__ cand32,
                                                    const int* __restrict__ cut,
                                                    u64* __restrict__ comp,
                                                    int* __restrict__ pos) {
    __shared__ int wbase[16];
    __shared__ int sbase;
    int m = blockIdx.y;
    int i = blockIdx.x * 1024 + threadIdx.x;
    int lane = threadIdx.x & 63, wid = threadIdx.x >> 6;
    unsigned cb = (i < NA) ? cand32[(size_t)m * NA + i] : 0u;
    int c = cut[m];
    bool keep = false;
    if (cb) keep = min(63, (int)((cb - 0x3F000000u) >> 17)) >= c;
    u64 bal = __ballot(keep);
    int cnt = __popcll(bal);
    if (lane == 0) wbase[wid] = cnt;
    __syncthreads();
    if (threadIdx.x == 0) {
        int s = 0;
        #pragma unroll
        for (int w = 0; w < 16; ++w) { int v = wbase[w]; wbase[w] = s; s += v; }
        sbase = s ? atomicAdd(&pos[m], s) : 0;
    }
    __syncthreads();
    if (keep) {
        int p = sbase + wbase[wid] + (int)__popcll(bal & ((1ull << lane) - 1ull));
        if (p < 4096)
            comp[(size_t)m * 4096 + p] = ((u64)cb << 32) | (u64)(0xFFFFFFFFu - (unsigned)i);
    }
}

// ---------------- K2c: 4096 bitonic sort desc -> sel + staged xyxy boxes ----------------
// strided ownership: thread owns {t, t+1024, t+2048, t+3072}; partner for dist j
// is thread t^j. SAFETY: at round j, buf[i^j] was written in round 2j by thread
// t^j or t^(j|2j) -> same-wave only if (j|2j) < 64, i.e. j < 32. Barrier at j>=32.
__global__ __launch_bounds__(1024) void k2c_sort(const u64* __restrict__ comp,
                                                 const int* __restrict__ pos,
                                                 const float* __restrict__ pred,
                                                 u64* __restrict__ sel,
                                                 float4* __restrict__ boxes) {
    __shared__ u64 buf[4096];
    int m   = blockIdx.x;
    int tid = threadIdx.x;
    int M = min(pos[m], 4096);
    const u64* c = comp + (size_t)m * 4096;
    #pragma unroll
    for (int r = 0; r < 4; ++r) {
        int i = tid + r * 1024;
        buf[i] = (i < M) ? c[i] : 0ull;         // 0 sentinel below all real keys
    }
    __syncthreads();
    for (int k = 2; k <= 4096; k <<= 1) {
        for (int j = k >> 1; j > 0; j >>= 1) {
            if (j >= 32) __syncthreads();
            #pragma unroll
            for (int r = 0; r < 4; ++r) {
                int i = tid + r * 1024;
                int l = i ^ j;
                if (l > i) {
                    u64 A = buf[i], B = buf[l];
                    bool up = ((i & k) == 0);
                    if (up ? (A < B) : (A > B)) { buf[i] = B; buf[l] = A; }
                }
            }
        }
    }
    __syncthreads();
    #pragma unroll
    for (int r = 0; r < 2; ++r) {
        int i = tid + r * 1024;
        u64 key = buf[i];
        sel[(size_t)m * TOPK + i] = key;
        float4 b = make_float4(0.f, 0.f, 0.f, 0.f);
        if (key) {
            unsigned idx = 0xFFFFFFFFu - (unsigned)(key & 0xFFFFFFFFull);
            const float4* rv = reinterpret_cast<const float4*>(pred + ((size_t)m * NA + idx) * 16);
            float4 v = rv[0];                   // [xc, yc, w, h]
            float hw = __fmul_rn(v.z, 0.5f), hh = __fmul_rn(v.w, 0.5f);
            b.x = __fsub_rn(v.x, hw);
            b.y = __fsub_rn(v.y, hh);
            b.z = __fadd_rn(v.x, hw);
            b.w = __fadd_rn(v.y, hh);
        }
        boxes[(size_t)m * TOPK + i] = b;
    }
}

// ---------------- K4: 2048x2048 suppression bitmask, TRANSPOSED (iou > 0.45) ----------------
// maskT[(m*32 + w)*2048 + row] : word w of row, stored word-major for coalesced
// per-word access in k5.
__global__ __launch_bounds__(1024) void k4_masks(const float4* __restrict__ boxes,
                                                 u64* __restrict__ maskT) {
    __shared__ float4 bx[TOPK];
    int m   = blockIdx.y;
    int grp = blockIdx.x;                       // 64 groups of 32 rows
    for (int i = threadIdx.x; i < TOPK; i += 1024)
        bx[i] = boxes[(size_t)m * TOPK + i];
    __syncthreads();

    int il = threadIdx.x & 31;
    int w  = threadIdx.x >> 5;
    int i  = grp * 32 + il;
    float4 b1 = bx[i];
    float a1 = __fmul_rn(__fsub_rn(b1.z, b1.x), __fsub_rn(b1.w, b1.y));
    u64 bits = 0ull;
    #pragma unroll 4
    for (int jj = 0; jj < 64; ++jj) {
        float4 b2 = bx[w * 64 + jj];
        float a2 = __fmul_rn(__fsub_rn(b2.z, b2.x), __fsub_rn(b2.w, b2.y));
        float iw = fmaxf(__fsub_rn(fminf(b1.z, b2.z), fmaxf(b1.x, b2.x)), 0.f);
        float ih = fmaxf(__fsub_rn(fminf(b1.w, b2.w), fmaxf(b1.y, b2.y)), 0.f);
        float inter = __fmul_rn(iw, ih);
        float uni   = __fsub_rn(__fadd_rn(a1, a2), inter);   // (a1+a2)-inter, ref order
        float iou   = __fdiv_rn(inter, uni);
        if (iou > 0.45f) bits |= (1ull << jj);
    }
    maskT[((size_t)m * 32 + w) * 2048 + i] = bits;
}

// ---------------- K5: greedy scan, prefetched incremental remv (1024 thr / image) ----------------
// Load addresses for the update phase are scan-independent: group w always needs
// rows blk*64+sub / +32 of word w. Prefetch next step's values before the first
// barrier (overlapping wave0's scan), then mask the registers with keep bits.
__global__ __launch_bounds__(1024) void k5_nms(const u64* __restrict__ sel,
                                               const u64* __restrict__ maskT,
                                               u64* __restrict__ keepmask) {
    __shared__ u64 remv[32];
    __shared__ u64 kbshare;
    int m = blockIdx.x;
    int t = threadIdx.x;
    int lane = t & 63;
    const u64* mt = maskT + (size_t)m * 32 * 2048;
    if (t < 32) remv[t] = 0ull;
    int w = t >> 5, sub = t & 31;
    u64 dval = 0ull, sval = 0ull;
    if (t < 64) {                               // wave 0: prefetch block 0 scan data
        dval = mt[(size_t)0 * 2048 + t];        // word 0, rows 0..63 (coalesced)
        sval = sel[(size_t)m * TOPK + t];
    }
    // prefetch step-0 update data (coalesced within each group)
    u64 pf0 = mt[(size_t)w * 2048 + sub];
    u64 pf1 = mt[(size_t)w * 2048 + sub + 32];
    __syncthreads();
    for (int blk = 0; blk < 32; ++blk) {
        // issue next step's update loads NOW (addresses scan-independent)
        u64 nf0 = 0ull, nf1 = 0ull;
        if (blk < 31) {
            int r0 = (blk + 1) * 64 + sub;
            nf0 = mt[(size_t)w * 2048 + r0];
            nf1 = mt[(size_t)w * 2048 + r0 + 32];
        }
        if (t < 64) {
            // ---- sequential scan of block blk (wave 0 only) ----
            u64 validw = __ballot(sval != 0ull);
            u64 acc = remv[blk];
            int sup = (int)((acc >> lane) & 1ull) | (int)(((~validw) >> lane) & 1ull);
            u64 kb = 0ull;
            u64 bal = __ballot(sup == 0);
            while (bal) {
                int j = __ffsll((long long)bal) - 1;
                kb |= (1ull << j);
                sup |= (int)((dval >> j) & 1ull);   // symmetry: row j suppresses lane?
                u64 low = (j < 63) ? ((2ull << j) - 1ull) : ~0ull;
                bal = __ballot(sup == 0) & ~low;    // low-mask guards NaN self-IoU
            }
            if (lane == 0) {
                kbshare = kb;
                keepmask[m * 32 + blk] = kb;
            }
            if (blk < 31) {                     // prefetch next block's scan data
                int r = (blk + 1) * 64 + lane;
                dval = mt[(size_t)(blk + 1) * 2048 + r];
                sval = sel[(size_t)m * TOPK + r];
            }
        }
        __syncthreads();
        // ---- parallel remv update: group w masks its prefetched registers ----
        if (w > blk) {
            u64 kb = kbshare;
            if (kb) {
                u64 v = (((kb >> sub) & 1ull) ? pf0 : 0ull)
                      | (((kb >> (sub + 32)) & 1ull) ? pf1 : 0ull);
                #pragma unroll
                for (int off = 1; off < 32; off <<= 1)
                    v |= __shfl_xor(v, off);    // reduce within 32-lane group
                if (sub == 0) remv[w] |= v;
            }
        }
        __syncthreads();
        pf0 = nf0; pf1 = nf1;
    }
}

// ---------------- K6: gather + write final output ----------------
__global__ void k6_out(const float* __restrict__ pred, const u64* __restrict__ sel,
                       const u64* __restrict__ keepmask, float4* __restrict__ out) {
    int gid = blockIdx.x * 256 + threadIdx.x;   // NIMG*TOPK*4 float4-chunks
    int c4 = gid & 3;
    int r  = (gid >> 2) & (TOPK - 1);
    int m  = gid >> 13;
    float4 o = make_float4(0.f, 0.f, 0.f, 0.f);
    if ((keepmask[m * 32 + (r >> 6)] >> (r & 63)) & 1ull) {
        u64 key = sel[(size_t)m * TOPK + r];
        unsigned idx = 0xFFFFFFFFu - (unsigned)(key & 0xFFFFFFFFull);
        const float4* rv = reinterpret_cast<const float4*>(pred + ((size_t)m * NA + idx) * 16);
        float4 v = rv[c4];
        if (c4 == 0) {
            float hw = __fmul_rn(v.z, 0.5f), hh = __fmul_rn(v.w, 0.5f);
            o = make_float4(__fsub_rn(v.x, hw), __fsub_rn(v.y, hh),
                            __fadd_rn(v.x, hw), __fadd_rn(v.y, hh));
        } else if (c4 == 1) {
            o = make_float4(__uint_as_float((unsigned)(key >> 32)), v.y, v.z, v.w);
        } else if (c4 == 2) {
            o = v;
        } else {
            o = make_float4(v.x, v.y, v.z, 0.f);
        }
    }
    out[gid] = o;
}

// ---------------- launch ----------------
extern "C" void kernel_launch(void* const* d_in, const int* in_sizes, int n_in,
                              void* d_out, int out_size, void* d_ws, size_t ws_size,
                              hipStream_t stream) {
    (void)in_sizes; (void)n_in; (void)out_size; (void)ws_size;
    const float* pred = (const float*)d_in[0];
    char* ws = (char*)d_ws;
    // layout (bytes):
    unsigned* cand32   = (unsigned*)(ws + 0);          // 8*100800*4 = 3,225,600
    u64*      comp     = (u64*)     (ws + 3225600);    // 8*4096*8   =   262,144
    u64*      sel      = (u64*)     (ws + 3487744);    // 8*2048*8   =   131,072
    float4*   boxes    = (float4*)  (ws + 3618816);    // 8*2048*16  =   262,144
    u64*      maskT    = (u64*)     (ws + 3880960);    // 8*32*2048*8= 4,194,304
    u64*      keepmask = (u64*)     (ws + 8075264);    // 8*32*8     =     2,048
    int*      histb    = (int*)     (ws + 8077312);    // 8*99*64*4  =   202,752
    int*      pos      = (int*)     (ws + 8280064);    // 32
    int*      cut      = (int*)     (ws + 8280096);    // 32
    float4*   out      = (float4*)d_out;

    hipLaunchKernelGGL(k1_scan,    dim3(NBLK1, NIMG),            dim3(256),  0, stream, pred, cand32, histb);
    hipLaunchKernelGGL(k2a_cutoff, dim3(NIMG),                   dim3(64),   0, stream, histb, cut, pos);
    hipLaunchKernelGGL(k2b_compact,dim3(NBLK1, NIMG),            dim3(1024), 0, stream, cand32, cut, comp, pos);
    hipLaunchKernelGGL(k2c_sort,   dim3(NIMG),                   dim3(1024), 0, stream, comp, pos, pred, sel, boxes);
    hipLaunchKernelGGL(k4_masks,   dim3(64, NIMG),               dim3(1024), 0, stream, boxes, maskT);
    hipLaunchKernelGGL(k5_nms,     dim3(NIMG),                   dim3(1024), 0, stream, sel, maskT, keepmask);
    hipLaunchKernelGGL(k6_out,     dim3(NIMG * TOPK * 4 / 256),  dim3(256),  0, stream, pred, sel, keepmask, out);
}

// Round 8
// 122.529 us; speedup vs baseline: 5.9801x; 1.3004x over previous
//
#include <hip/hip_runtime.h>
#include <stdint.h>

#define NA    100800
#define NIMG  8
#define TOPK  2048
#define NBLK1 99              // ceil(NA / 1024)
typedef unsigned long long u64;

// ---------------- K1: coalesced scan -> dense conf-bits + per-block LDS hist ----------------
// Row = 64 B = 4 float4s; we need quarter#1 (obj at .x) and quarter#3 (x15 at .w):
// exactly the ODD float4 indices. Thread t loads f4[2t+1] and f4[2t+513] (dense),
// __shfl_xor(1) pairs obj with x15. Even lane finalizes rows r and r+128.
__global__ __launch_bounds__(256) void k1_scan(const float* __restrict__ pred,
                                               unsigned* __restrict__ cand32,
                                               int* __restrict__ hist_blocks) {
    __shared__ int lhist[64];
    int t = threadIdx.x;
    int m = blockIdx.y;
    if (t < 64) lhist[t] = 0;
    __syncthreads();
    const float4* p4 = reinterpret_cast<const float4*>(pred + (size_t)m * NA * 16);
    int row0blk = blockIdx.x * 1024;
    for (int pass = 0; pass < 4; ++pass) {
        int row0 = row0blk + pass * 256;
        int i1 = row0 * 4 + 2 * t + 1;
        int i2 = i1 + 512;
        float4 A = make_float4(0.f, 0.f, 0.f, 0.f);
        float4 B = make_float4(0.f, 0.f, 0.f, 0.f);
        if ((i1 >> 2) < NA) A = p4[i1];
        if ((i2 >> 2) < NA) B = p4[i2];
        float aw = __shfl_xor(A.w, 1);          // x15 of row rA (valid on even lanes)
        float bw = __shfl_xor(B.w, 1);          // x15 of row rB
        if (!(t & 1)) {
            int rA = row0 + (t >> 1);
            int rB = rA + 128;
            {
                float obj = A.x, x15 = aw;
                if (rA < NA) {
                    float conf = __fmul_rn(x15, obj);   // exact ref op
                    unsigned cb = 0u;
                    if (obj > 0.5f && conf > 0.5f) {
                        cb = __float_as_uint(conf);
                        atomicAdd(&lhist[min(63, (int)((cb - 0x3F000000u) >> 17))], 1);
                    }
                    cand32[(size_t)m * NA + rA] = cb;
                }
            }
            {
                float obj = B.x, x15 = bw;
                if (rB < NA) {
                    float conf = __fmul_rn(x15, obj);
                    unsigned cb = 0u;
                    if (obj > 0.5f && conf > 0.5f) {
                        cb = __float_as_uint(conf);
                        atomicAdd(&lhist[min(63, (int)((cb - 0x3F000000u) >> 17))], 1);
                    }
                    cand32[(size_t)m * NA + rB] = cb;
                }
            }
        }
    }
    __syncthreads();
    if (t < 64) hist_blocks[((size_t)m * NBLK1 + blockIdx.x) * 64 + t] = lhist[t];
}

// ---------------- K2a: reduce per-block hists + cutoff via suffix-scan (1 wave/image) ----------------
__global__ void k2a_cutoff(const int* __restrict__ hist_blocks, int* __restrict__ cut,
                           int* __restrict__ pos) {
    int m = blockIdx.x;
    int lane = threadIdx.x;                     // 64 threads
    int h = 0;
    #pragma unroll 4
    for (int b = 0; b < NBLK1; ++b)             // coalesced: 64 consecutive ints per b
        h += hist_blocks[((size_t)m * NBLK1 + b) * 64 + lane];
    #pragma unroll
    for (int off = 1; off < 64; off <<= 1) {    // inclusive suffix sum
        int src = lane + off;
        int v = __shfl(h, src < 64 ? src : lane);
        h += (src < 64) ? v : 0;
    }
    int total  = __shfl(h, 0);
    int needed = min(total, TOPK);
    u64 bal = __ballot(h >= needed);
    int cutoff = 63 - __clzll(bal);             // highest bin with suffix >= needed
    if (lane == 0) { cut[m] = cutoff; pos[m] = 0; }
}

// ---------------- K2b: compact bin>=cutoff; ONE atomic per 1024-thread block ----------------
__global__ __launch_bounds__(1024) void k2b_compact(const unsigned* __restrict__ cand32,
                                                    const int* __restrict__ cut,
                                                    u64* __restrict__ comp,
                                                    int* __restrict__ pos) {
    __shared__ int wbase[16];
    __shared__ int sbase;
    int m = blockIdx.y;
    int i = blockIdx.x * 1024 + threadIdx.x;
    int lane = threadIdx.x & 63, wid = threadIdx.x >> 6;
    unsigned cb = (i < NA) ? cand32[(size_t)m * NA + i] : 0u;
    int c = cut[m];
    bool keep = false;
    if (cb) keep = min(63, (int)((cb - 0x3F000000u) >> 17)) >= c;
    u64 bal = __ballot(keep);
    int cnt = __popcll(bal);
    if (lane == 0) wbase[wid] = cnt;
    __syncthreads();
    if (threadIdx.x == 0) {
        int s = 0;
        #pragma unroll
        for (int w = 0; w < 16; ++w) { int v = wbase[w]; wbase[w] = s; s += v; }
        sbase = s ? atomicAdd(&pos[m], s) : 0;
    }
    __syncthreads();
    if (keep) {
        int p = sbase + wbase[wid] + (int)__popcll(bal & ((1ull << lane) - 1ull));
        if (p < 4096)
            comp[(size_t)m * 4096 + p] = ((u64)cb << 32) | (u64)(0xFFFFFFFFu - (unsigned)i);
    }
}

// ---------------- K2c: counting-rank (4096 fine bins) -> sel + staged boxes ----------------
// rbin = 4095 - (mantissa>>11): bin 0 = highest conf. Prefix-sum bin counts,
// atomic scatter within bin, then deterministic per-bin insertion sort (keys
// unique -> final order independent of atomic order). Replaces bitonic sort.
__global__ __launch_bounds__(1024) void k2c_rank(const u64* __restrict__ comp,
                                                 const int* __restrict__ pos,
                                                 const float* __restrict__ pred,
                                                 u64* __restrict__ sel,
                                                 float4* __restrict__ boxes) {
    __shared__ int fcnt[4096];
    __shared__ int fstart[4096];
    __shared__ u64 outb[4096];
    __shared__ int wsum[16];
    int m = blockIdx.x, t = threadIdx.x;
    int M = min(pos[m], 4096);
    const u64* c = comp + (size_t)m * 4096;
    #pragma unroll
    for (int r = 0; r < 4; ++r) { fcnt[t + r * 1024] = 0; outb[t + r * 1024] = 0ull; }
    __syncthreads();
    // phase 1: load keys (strided, coalesced) + fine histogram
    u64 kk[4]; int rb[4];
    #pragma unroll
    for (int r = 0; r < 4; ++r) {
        int i = t + r * 1024;
        kk[r] = 0ull; rb[r] = -1;
        if (i < M) {
            kk[r] = c[i];
            rb[r] = 4095 - (int)(((unsigned)(kk[r] >> 32) - 0x3F000000u) >> 11);
            atomicAdd(&fcnt[rb[r]], 1);
        }
    }
    __syncthreads();
    // phase 2: exclusive prefix sum over 4096 bins (thread t owns bins 4t..4t+3)
    int c0 = fcnt[4 * t], c1 = fcnt[4 * t + 1], c2 = fcnt[4 * t + 2], c3 = fcnt[4 * t + 3];
    int s = c0 + c1 + c2 + c3;
    int lane = t & 63, w = t >> 6;
    int incl = s;
    #pragma unroll
    for (int off = 1; off < 64; off <<= 1) {
        int v = __shfl_up(incl, off);
        if (lane >= off) incl += v;
    }
    if (lane == 63) wsum[w] = incl;
    __syncthreads();
    if (w == 0) {
        int v = (lane < 16) ? wsum[lane] : 0;
        #pragma unroll
        for (int off = 1; off < 16; off <<= 1) {
            int u = __shfl_up(v, off);
            if (lane >= off) v += u;
        }
        if (lane < 16) wsum[lane] = v;     // inclusive wave sums
    }
    __syncthreads();
    int base = (w > 0 ? wsum[w - 1] : 0) + (incl - s);
    fstart[4 * t]     = base;
    fstart[4 * t + 1] = base + c0;
    fstart[4 * t + 2] = base + c0 + c1;
    fstart[4 * t + 3] = base + c0 + c1 + c2;
    __syncthreads();
    // phase 3: scatter (slot order within bin arbitrary; fixed in phase 4)
    #pragma unroll
    for (int r = 0; r < 4; ++r) {
        if (rb[r] >= 0) {
            int old = atomicSub(&fcnt[rb[r]], 1);
            int slot = fstart[rb[r]] + old - 1;
            outb[slot] = kk[r];
        }
    }
    __syncthreads();
    // phase 4: deterministic cleanup — insertion-sort each bin's range desc
    #pragma unroll
    for (int r = 0; r < 4; ++r) {
        int b = t + r * 1024;
        int st = fstart[b];
        int en = (b < 4095) ? fstart[b + 1] : M;
        for (int x = st + 1; x < en; ++x) {
            u64 key = outb[x];
            int y = x - 1;
            while (y >= st && outb[y] < key) { outb[y + 1] = outb[y]; --y; }
            outb[y + 1] = key;
        }
    }
    __syncthreads();
    // phase 5: emit sel + staged xyxy boxes for top-2048
    #pragma unroll
    for (int r = 0; r < 2; ++r) {
        int i = t + r * 1024;
        u64 key = outb[i];
        sel[(size_t)m * TOPK + i] = key;
        float4 b = make_float4(0.f, 0.f, 0.f, 0.f);
        if (key) {
            unsigned idx = 0xFFFFFFFFu - (unsigned)(key & 0xFFFFFFFFull);
            const float4* rv = reinterpret_cast<const float4*>(pred + ((size_t)m * NA + idx) * 16);
            float4 v = rv[0];                   // [xc, yc, w, h]
            float hw = __fmul_rn(v.z, 0.5f), hh = __fmul_rn(v.w, 0.5f);
            b.x = __fsub_rn(v.x, hw);
            b.y = __fsub_rn(v.y, hh);
            b.z = __fadd_rn(v.x, hw);
            b.w = __fadd_rn(v.y, hh);
        }
        boxes[(size_t)m * TOPK + i] = b;
    }
}

// ---------------- K4: 2048x2048 suppression bitmask, TRANSPOSED (iou > 0.45) ----------------
// maskT[(m*32 + w)*2048 + row] : word w of row, stored word-major for coalesced
// per-word access in k5.
__global__ __launch_bounds__(1024) void k4_masks(const float4* __restrict__ boxes,
                                                 u64* __restrict__ maskT) {
    __shared__ float4 bx[TOPK];
    int m   = blockIdx.y;
    int grp = blockIdx.x;                       // 64 groups of 32 rows
    for (int i = threadIdx.x; i < TOPK; i += 1024)
        bx[i] = boxes[(size_t)m * TOPK + i];
    __syncthreads();

    int il = threadIdx.x & 31;
    int w  = threadIdx.x >> 5;
    int i  = grp * 32 + il;
    float4 b1 = bx[i];
    float a1 = __fmul_rn(__fsub_rn(b1.z, b1.x), __fsub_rn(b1.w, b1.y));
    u64 bits = 0ull;
    #pragma unroll 4
    for (int jj = 0; jj < 64; ++jj) {
        float4 b2 = bx[w * 64 + jj];
        float a2 = __fmul_rn(__fsub_rn(b2.z, b2.x), __fsub_rn(b2.w, b2.y));
        float iw = fmaxf(__fsub_rn(fminf(b1.z, b2.z), fmaxf(b1.x, b2.x)), 0.f);
        float ih = fmaxf(__fsub_rn(fminf(b1.w, b2.w), fmaxf(b1.y, b2.y)), 0.f);
        float inter = __fmul_rn(iw, ih);
        float uni   = __fsub_rn(__fadd_rn(a1, a2), inter);   // (a1+a2)-inter, ref order
        float iou   = __fdiv_rn(inter, uni);
        if (iou > 0.45f) bits |= (1ull << jj);
    }
    maskT[((size_t)m * 32 + w) * 2048 + i] = bits;
}

// ---------------- K5: greedy scan, prefetched incremental remv (1024 thr / image) ----------------
// Load addresses for the update phase are scan-independent: group w always needs
// rows blk*64+sub / +32 of word w. Prefetch next step's values before the first
// barrier (overlapping wave0's scan), then mask the registers with keep bits.
__global__ __launch_bounds__(1024) void k5_nms(const u64* __restrict__ sel,
                                               const u64* __restrict__ maskT,
                                               u64* __restrict__ keepmask) {
    __shared__ u64 remv[32];
    __shared__ u64 kbshare;
    int m = blockIdx.x;
    int t = threadIdx.x;
    int lane = t & 63;
    const u64* mt = maskT + (size_t)m * 32 * 2048;
    if (t < 32) remv[t] = 0ull;
    int w = t >> 5, sub = t & 31;
    u64 dval = 0ull, sval = 0ull;
    if (t < 64) {                               // wave 0: prefetch block 0 scan data
        dval = mt[(size_t)0 * 2048 + t];        // word 0, rows 0..63 (coalesced)
        sval = sel[(size_t)m * TOPK + t];
    }
    // prefetch step-0 update data (coalesced within each group)
    u64 pf0 = mt[(size_t)w * 2048 + sub];
    u64 pf1 = mt[(size_t)w * 2048 + sub + 32];
    __syncthreads();
    for (int blk = 0; blk < 32; ++blk) {
        // issue next step's update loads NOW (addresses scan-independent)
        u64 nf0 = 0ull, nf1 = 0ull;
        if (blk < 31) {
            int r0 = (blk + 1) * 64 + sub;
            nf0 = mt[(size_t)w * 2048 + r0];
            nf1 = mt[(size_t)w * 2048 + r0 + 32];
        }
        if (t < 64) {
            // ---- sequential scan of block blk (wave 0 only) ----
            u64 validw = __ballot(sval != 0ull);
            u64 acc = remv[blk];
            int sup = (int)((acc >> lane) & 1ull) | (int)(((~validw) >> lane) & 1ull);
            u64 kb = 0ull;
            u64 bal = __ballot(sup == 0);
            while (bal) {
                int j = __ffsll((long long)bal) - 1;
                kb |= (1ull << j);
                sup |= (int)((dval >> j) & 1ull);   // symmetry: row j suppresses lane?
                u64 low = (j < 63) ? ((2ull << j) - 1ull) : ~0ull;
                bal = __ballot(sup == 0) & ~low;    // low-mask guards NaN self-IoU
            }
            if (lane == 0) {
                kbshare = kb;
                keepmask[m * 32 + blk] = kb;
            }
            if (blk < 31) {                     // prefetch next block's scan data
                int r = (blk + 1) * 64 + lane;
                dval = mt[(size_t)(blk + 1) * 2048 + r];
                sval = sel[(size_t)m * TOPK + r];
            }
        }
        __syncthreads();
        // ---- parallel remv update: group w masks its prefetched registers ----
        if (w > blk) {
            u64 kb = kbshare;
            if (kb) {
                u64 v = (((kb >> sub) & 1ull) ? pf0 : 0ull)
                      | (((kb >> (sub + 32)) & 1ull) ? pf1 : 0ull);
                #pragma unroll
                for (int off = 1; off < 32; off <<= 1)
                    v |= __shfl_xor(v, off);    // reduce within 32-lane group
                if (sub == 0) remv[w] |= v;
            }
        }
        __syncthreads();
        pf0 = nf0; pf1 = nf1;
    }
}

// ---------------- K6: gather + write final output ----------------
__global__ void k6_out(const float* __restrict__ pred, const u64* __restrict__ sel,
                       const u64* __restrict__ keepmask, float4* __restrict__ out) {
    int gid = blockIdx.x * 256 + threadIdx.x;   // NIMG*TOPK*4 float4-chunks
    int c4 = gid & 3;
    int r  = (gid >> 2) & (TOPK - 1);
    int m  = gid >> 13;
    float4 o = make_float4(0.f, 0.f, 0.f, 0.f);
    if ((keepmask[m * 32 + (r >> 6)] >> (r & 63)) & 1ull) {
        u64 key = sel[(size_t)m * TOPK + r];
        unsigned idx = 0xFFFFFFFFu - (unsigned)(key & 0xFFFFFFFFull);
        const float4* rv = reinterpret_cast<const float4*>(pred + ((size_t)m * NA + idx) * 16);
        float4 v = rv[c4];
        if (c4 == 0) {
            float hw = __fmul_rn(v.z, 0.5f), hh = __fmul_rn(v.w, 0.5f);
            o = make_float4(__fsub_rn(v.x, hw), __fsub_rn(v.y, hh),
                            __fadd_rn(v.x, hw), __fadd_rn(v.y, hh));
        } else if (c4 == 1) {
            o = make_float4(__uint_as_float((unsigned)(key >> 32)), v.y, v.z, v.w);
        } else if (c4 == 2) {
            o = v;
        } else {
            o = make_float4(v.x, v.y, v.z, 0.f);
        }
    }
    out[gid] = o;
}

// ---------------- launch ----------------
extern "C" void kernel_launch(void* const* d_in, const int* in_sizes, int n_in,
                              void* d_out, int out_size, void* d_ws, size_t ws_size,
                              hipStream_t stream) {
    (void)in_sizes; (void)n_in; (void)out_size; (void)ws_size;
    const float* pred = (const float*)d_in[0];
    char* ws = (char*)d_ws;
    // layout (bytes):
    unsigned* cand32   = (unsigned*)(ws + 0);          // 8*100800*4 = 3,225,600
    u64*      comp     = (u64*)     (ws + 3225600);    // 8*4096*8   =   262,144
    u64*      sel      = (u64*)     (ws + 3487744);    // 8*2048*8   =   131,072
    float4*   boxes    = (float4*)  (ws + 3618816);    // 8*2048*16  =   262,144
    u64*      maskT    = (u64*)     (ws + 3880960);    // 8*32*2048*8= 4,194,304
    u64*      keepmask = (u64*)     (ws + 8075264);    // 8*32*8     =     2,048
    int*      histb    = (int*)     (ws + 8077312);    // 8*99*64*4  =   202,752
    int*      pos      = (int*)     (ws + 8280064);    // 32
    int*      cut      = (int*)     (ws + 8280096);    // 32
    float4*   out      = (float4*)d_out;

    hipLaunchKernelGGL(k1_scan,    dim3(NBLK1, NIMG),            dim3(256),  0, stream, pred, cand32, histb);
    hipLaunchKernelGGL(k2a_cutoff, dim3(NIMG),                   dim3(64),   0, stream, histb, cut, pos);
    hipLaunchKernelGGL(k2b_compact,dim3(NBLK1, NIMG),            dim3(1024), 0, stream, cand32, cut, comp, pos);
    hipLaunchKernelGGL(k2c_rank,   dim3(NIMG),                   dim3(1024), 0, stream, comp, pos, pred, sel, boxes);
    hipLaunchKernelGGL(k4_masks,   dim3(64, NIMG),               dim3(1024), 0, stream, boxes, maskT);
    hipLaunchKernelGGL(k5_nms,     dim3(NIMG),                   dim3(1024), 0, stream, sel, maskT, keepmask);
    hipLaunchKernelGGL(k6_out,     dim3(NIMG * TOPK * 4 / 256),  dim3(256),  0, stream, pred, sel, keepmask, out);
}

// Round 9
// 119.499 us; speedup vs baseline: 6.1317x; 1.0253x over previous
//
#include <hip/hip_runtime.h>
#include <stdint.h>

#define NA    100800
#define NIMG  8
#define TOPK  2048
#define NBLK1 99              // ceil(NA / 1024)
typedef unsigned long long u64;

// ---------------- K1: coalesced scan -> dense conf-bits + per-block LDS hist ----------------
// Row = 64 B = 4 float4s; we need quarter#1 (obj at .x) and quarter#3 (x15 at .w):
// exactly the ODD float4 indices. Thread t loads f4[2t+1] and f4[2t+513] (dense),
// __shfl_xor(1) pairs obj with x15. Even lane finalizes rows r and r+128.
__global__ __launch_bounds__(256) void k1_scan(const float* __restrict__ pred,
                                               unsigned* __restrict__ cand32,
                                               int* __restrict__ hist_blocks) {
    __shared__ int lhist[64];
    int t = threadIdx.x;
    int m = blockIdx.y;
    if (t < 64) lhist[t] = 0;
    __syncthreads();
    const float4* p4 = reinterpret_cast<const float4*>(pred + (size_t)m * NA * 16);
    int row0blk = blockIdx.x * 1024;
    for (int pass = 0; pass < 4; ++pass) {
        int row0 = row0blk + pass * 256;
        int i1 = row0 * 4 + 2 * t + 1;
        int i2 = i1 + 512;
        float4 A = make_float4(0.f, 0.f, 0.f, 0.f);
        float4 B = make_float4(0.f, 0.f, 0.f, 0.f);
        if ((i1 >> 2) < NA) A = p4[i1];
        if ((i2 >> 2) < NA) B = p4[i2];
        float aw = __shfl_xor(A.w, 1);          // x15 of row rA (valid on even lanes)
        float bw = __shfl_xor(B.w, 1);          // x15 of row rB
        if (!(t & 1)) {
            int rA = row0 + (t >> 1);
            int rB = rA + 128;
            {
                float obj = A.x, x15 = aw;
                if (rA < NA) {
                    float conf = __fmul_rn(x15, obj);   // exact ref op
                    unsigned cb = 0u;
                    if (obj > 0.5f && conf > 0.5f) {
                        cb = __float_as_uint(conf);
                        atomicAdd(&lhist[min(63, (int)((cb - 0x3F000000u) >> 17))], 1);
                    }
                    cand32[(size_t)m * NA + rA] = cb;
                }
            }
            {
                float obj = B.x, x15 = bw;
                if (rB < NA) {
                    float conf = __fmul_rn(x15, obj);
                    unsigned cb = 0u;
                    if (obj > 0.5f && conf > 0.5f) {
                        cb = __float_as_uint(conf);
                        atomicAdd(&lhist[min(63, (int)((cb - 0x3F000000u) >> 17))], 1);
                    }
                    cand32[(size_t)m * NA + rB] = cb;
                }
            }
        }
    }
    __syncthreads();
    if (t < 64) hist_blocks[((size_t)m * NBLK1 + blockIdx.x) * 64 + t] = lhist[t];
}

// ---------------- K2a: reduce per-block hists + cutoff via suffix-scan (1 wave/image) ----------------
__global__ void k2a_cutoff(const int* __restrict__ hist_blocks, int* __restrict__ cut,
                           int* __restrict__ pos) {
    int m = blockIdx.x;
    int lane = threadIdx.x;                     // 64 threads
    int h = 0;
    #pragma unroll 4
    for (int b = 0; b < NBLK1; ++b)             // coalesced: 64 consecutive ints per b
        h += hist_blocks[((size_t)m * NBLK1 + b) * 64 + lane];
    #pragma unroll
    for (int off = 1; off < 64; off <<= 1) {    // inclusive suffix sum
        int src = lane + off;
        int v = __shfl(h, src < 64 ? src : lane);
        h += (src < 64) ? v : 0;
    }
    int total  = __shfl(h, 0);
    int needed = min(total, TOPK);
    u64 bal = __ballot(h >= needed);
    int cutoff = 63 - __clzll(bal);             // highest bin with suffix >= needed
    if (lane == 0) { cut[m] = cutoff; pos[m] = 0; }
}

// ---------------- K2b: compact bin>=cutoff; ONE atomic per 1024-thread block ----------------
__global__ __launch_bounds__(1024) void k2b_compact(const unsigned* __restrict__ cand32,
                                                    const int* __restrict__ cut,
                                                    u64* __restrict__ comp,
                                                    int* __restrict__ pos) {
    __shared__ int wbase[16];
    __shared__ int sbase;
    int m = blockIdx.y;
    int i = blockIdx.x * 1024 + threadIdx.x;
    int lane = threadIdx.x & 63, wid = threadIdx.x >> 6;
    unsigned cb = (i < NA) ? cand32[(size_t)m * NA + i] : 0u;
    int c = cut[m];
    bool keep = false;
    if (cb) keep = min(63, (int)((cb - 0x3F000000u) >> 17)) >= c;
    u64 bal = __ballot(keep);
    int cnt = __popcll(bal);
    if (lane == 0) wbase[wid] = cnt;
    __syncthreads();
    if (threadIdx.x == 0) {
        int s = 0;
        #pragma unroll
        for (int w = 0; w < 16; ++w) { int v = wbase[w]; wbase[w] = s; s += v; }
        sbase = s ? atomicAdd(&pos[m], s) : 0;
    }
    __syncthreads();
    if (keep) {
        int p = sbase + wbase[wid] + (int)__popcll(bal & ((1ull << lane) - 1ull));
        if (p < 4096)
            comp[(size_t)m * 4096 + p] = ((u64)cb << 32) | (u64)(0xFFFFFFFFu - (unsigned)i);
    }
}

// ---------------- K2c: counting-rank (4096 fine bins) -> sel + staged boxes ----------------
// rbin = 4095 - (mantissa>>11): bin 0 = highest conf. Prefix-sum bin counts,
// atomic scatter within bin, then deterministic per-bin insertion sort (keys
// unique -> final order independent of atomic order). Replaces bitonic sort.
__global__ __launch_bounds__(1024) void k2c_rank(const u64* __restrict__ comp,
                                                 const int* __restrict__ pos,
                                                 const float* __restrict__ pred,
                                                 u64* __restrict__ sel,
                                                 float4* __restrict__ boxes) {
    __shared__ int fcnt[4096];
    __shared__ int fstart[4096];
    __shared__ u64 outb[4096];
    __shared__ int wsum[16];
    int m = blockIdx.x, t = threadIdx.x;
    int M = min(pos[m], 4096);
    const u64* c = comp + (size_t)m * 4096;
    #pragma unroll
    for (int r = 0; r < 4; ++r) { fcnt[t + r * 1024] = 0; outb[t + r * 1024] = 0ull; }
    __syncthreads();
    // phase 1: load keys (strided, coalesced) + fine histogram
    u64 kk[4]; int rb[4];
    #pragma unroll
    for (int r = 0; r < 4; ++r) {
        int i = t + r * 1024;
        kk[r] = 0ull; rb[r] = -1;
        if (i < M) {
            kk[r] = c[i];
            rb[r] = 4095 - (int)(((unsigned)(kk[r] >> 32) - 0x3F000000u) >> 11);
            atomicAdd(&fcnt[rb[r]], 1);
        }
    }
    __syncthreads();
    // phase 2: exclusive prefix sum over 4096 bins (thread t owns bins 4t..4t+3)
    int c0 = fcnt[4 * t], c1 = fcnt[4 * t + 1], c2 = fcnt[4 * t + 2], c3 = fcnt[4 * t + 3];
    int s = c0 + c1 + c2 + c3;
    int lane = t & 63, w = t >> 6;
    int incl = s;
    #pragma unroll
    for (int off = 1; off < 64; off <<= 1) {
        int v = __shfl_up(incl, off);
        if (lane >= off) incl += v;
    }
    if (lane == 63) wsum[w] = incl;
    __syncthreads();
    if (w == 0) {
        int v = (lane < 16) ? wsum[lane] : 0;
        #pragma unroll
        for (int off = 1; off < 16; off <<= 1) {
            int u = __shfl_up(v, off);
            if (lane >= off) v += u;
        }
        if (lane < 16) wsum[lane] = v;     // inclusive wave sums
    }
    __syncthreads();
    int base = (w > 0 ? wsum[w - 1] : 0) + (incl - s);
    fstart[4 * t]     = base;
    fstart[4 * t + 1] = base + c0;
    fstart[4 * t + 2] = base + c0 + c1;
    fstart[4 * t + 3] = base + c0 + c1 + c2;
    __syncthreads();
    // phase 3: scatter (slot order within bin arbitrary; fixed in phase 4)
    #pragma unroll
    for (int r = 0; r < 4; ++r) {
        if (rb[r] >= 0) {
            int old = atomicSub(&fcnt[rb[r]], 1);
            int slot = fstart[rb[r]] + old - 1;
            outb[slot] = kk[r];
        }
    }
    __syncthreads();
    // phase 4: deterministic cleanup — insertion-sort each bin's range desc
    #pragma unroll
    for (int r = 0; r < 4; ++r) {
        int b = t + r * 1024;
        int st = fstart[b];
        int en = (b < 4095) ? fstart[b + 1] : M;
        for (int x = st + 1; x < en; ++x) {
            u64 key = outb[x];
            int y = x - 1;
            while (y >= st && outb[y] < key) { outb[y + 1] = outb[y]; --y; }
            outb[y + 1] = key;
        }
    }
    __syncthreads();
    // phase 5: emit sel + staged xyxy boxes for top-2048
    #pragma unroll
    for (int r = 0; r < 2; ++r) {
        int i = t + r * 1024;
        u64 key = outb[i];
        sel[(size_t)m * TOPK + i] = key;
        float4 b = make_float4(0.f, 0.f, 0.f, 0.f);
        if (key) {
            unsigned idx = 0xFFFFFFFFu - (unsigned)(key & 0xFFFFFFFFull);
            const float4* rv = reinterpret_cast<const float4*>(pred + ((size_t)m * NA + idx) * 16);
            float4 v = rv[0];                   // [xc, yc, w, h]
            float hw = __fmul_rn(v.z, 0.5f), hh = __fmul_rn(v.w, 0.5f);
            b.x = __fsub_rn(v.x, hw);
            b.y = __fsub_rn(v.y, hh);
            b.z = __fadd_rn(v.x, hw);
            b.w = __fadd_rn(v.y, hh);
        }
        boxes[(size_t)m * TOPK + i] = b;
    }
}

// ---------------- K4: 2048x2048 suppression bitmask, TRANSPOSED (iou > 0.45) ----------------
// maskT[(m*32 + w)*2048 + row] : word w of row, stored word-major for coalesced
// per-word access in k5.
__global__ __launch_bounds__(1024) void k4_masks(const float4* __restrict__ boxes,
                                                 u64* __restrict__ maskT) {
    __shared__ float4 bx[TOPK];
    int m   = blockIdx.y;
    int grp = blockIdx.x;                       // 64 groups of 32 rows
    for (int i = threadIdx.x; i < TOPK; i += 1024)
        bx[i] = boxes[(size_t)m * TOPK + i];
    __syncthreads();

    int il = threadIdx.x & 31;
    int w  = threadIdx.x >> 5;
    int i  = grp * 32 + il;
    float4 b1 = bx[i];
    float a1 = __fmul_rn(__fsub_rn(b1.z, b1.x), __fsub_rn(b1.w, b1.y));
    u64 bits = 0ull;
    #pragma unroll 4
    for (int jj = 0; jj < 64; ++jj) {
        float4 b2 = bx[w * 64 + jj];
        float a2 = __fmul_rn(__fsub_rn(b2.z, b2.x), __fsub_rn(b2.w, b2.y));
        float iw = fmaxf(__fsub_rn(fminf(b1.z, b2.z), fmaxf(b1.x, b2.x)), 0.f);
        float ih = fmaxf(__fsub_rn(fminf(b1.w, b2.w), fmaxf(b1.y, b2.y)), 0.f);
        float inter = __fmul_rn(iw, ih);
        float uni   = __fsub_rn(__fadd_rn(a1, a2), inter);   // (a1+a2)-inter, ref order
        float iou   = __fdiv_rn(inter, uni);
        if (iou > 0.45f) bits |= (1ull << jj);
    }
    maskT[((size_t)m * 32 + w) * 2048 + i] = bits;
}

// ---------------- K5: greedy scan, ballot-based lagged updates (1024 thr / image) ----------------
// One barrier per step. Wave 0 scans block blk; waves 1..15 simultaneously apply
// block blk-1's keep-word (kbshare, double-buffered) to remv words blk+1..31:
// by IoU symmetry, contribution bit_lane = (maskT[blk-1][w*64+lane] & kb) != 0,
// packed by one __ballot — no shfl reduce. The one contribution that can't lag,
// C(blk, blk+1), is wave 0's per-lane flag (tval & kb) != 0 (also symmetry).
__global__ __launch_bounds__(1024) void k5_nms(const u64* __restrict__ sel,
                                               const u64* __restrict__ maskT,
                                               u64* __restrict__ keepmask) {
    __shared__ u64 remv[32];
    __shared__ u64 kbshare[2];
    int m = blockIdx.x;
    int t = threadIdx.x;
    int lane = t & 63;
    int wv = t >> 6;                            // wave id 0..15
    const u64* mt = maskT + (size_t)m * 32 * 2048;
    if (t < 32) remv[t] = 0ull;
    u64 dval = 0ull, sval = 0ull, tval = 0ull;
    int cflag = 0;                              // per-lane: row blk*64+lane suppressed by block blk-1's kept
    if (wv == 0) {
        dval = mt[(size_t)0 * 2048 + lane];     // word 0, rows 0..63 (diag)
        sval = sel[(size_t)m * TOPK + lane];
        tval = mt[(size_t)0 * 2048 + 64 + lane];// word 0, rows 64..127 (for C(0,1))
    }
    __syncthreads();
    for (int blk = 0; blk < 32; ++blk) {
        if (wv == 0) {
            // issue next step's loads first (addresses scan-independent)
            u64 dn = 0ull, sn = 0ull, tn = 0ull;
            if (blk < 31) {
                int r = (blk + 1) * 64 + lane;
                dn = mt[(size_t)(blk + 1) * 2048 + r];
                sn = sel[(size_t)m * TOPK + r];
                if (blk < 30) tn = mt[(size_t)(blk + 1) * 2048 + r + 64];
            }
            // ---- scan block blk ----
            u64 ext = remv[blk];
            u64 validw = __ballot(sval != 0ull);
            int sup = (int)((ext >> lane) & 1ull) | cflag
                    | (int)(((~validw) >> lane) & 1ull);
            u64 kb = 0ull;
            u64 bal = __ballot(sup == 0);
            while (bal) {
                int j = __ffsll((long long)bal) - 1;
                kb |= (1ull << j);
                sup |= (int)((dval >> j) & 1ull);   // symmetry: row j suppresses lane?
                u64 low = (j < 63) ? ((2ull << j) - 1ull) : ~0ull;
                bal = __ballot(sup == 0) & ~low;    // low-mask guards NaN self-IoU
            }
            cflag = (blk < 31 && (tval & kb)) ? 1 : 0;  // C(blk, blk+1), per-lane
            if (lane == 0) {
                kbshare[blk & 1] = kb;
                keepmask[m * 32 + blk] = kb;
            }
            dval = dn; sval = sn; tval = tn;
        } else if (blk >= 1) {
            // ---- lagged update: apply kb[blk-1] to words blk+1..31 ----
            u64 kb = kbshare[(blk - 1) & 1];
            int w1 = blk + wv;                  // blk+1 .. blk+15
            int w2 = blk + 15 + wv;             // blk+16 .. blk+30
            u64 v1 = (w1 < 32) ? mt[(size_t)(blk - 1) * 2048 + w1 * 64 + lane] : 0ull;
            u64 v2 = (w2 < 32) ? mt[(size_t)(blk - 1) * 2048 + w2 * 64 + lane] : 0ull;
            u64 c1 = __ballot((v1 & kb) != 0ull);
            u64 c2 = __ballot((v2 & kb) != 0ull);
            if (w1 < 32 && lane == 0) remv[w1] |= c1;
            if (w2 < 32 && lane == 0) remv[w2] |= c2;
        }
        __syncthreads();
    }
}

// ---------------- K6: gather + write final output ----------------
__global__ void k6_out(const float* __restrict__ pred, const u64* __restrict__ sel,
                       const u64* __restrict__ keepmask, float4* __restrict__ out) {
    int gid = blockIdx.x * 256 + threadIdx.x;   // NIMG*TOPK*4 float4-chunks
    int c4 = gid & 3;
    int r  = (gid >> 2) & (TOPK - 1);
    int m  = gid >> 13;
    float4 o = make_float4(0.f, 0.f, 0.f, 0.f);
    if ((keepmask[m * 32 + (r >> 6)] >> (r & 63)) & 1ull) {
        u64 key = sel[(size_t)m * TOPK + r];
        unsigned idx = 0xFFFFFFFFu - (unsigned)(key & 0xFFFFFFFFull);
        const float4* rv = reinterpret_cast<const float4*>(pred + ((size_t)m * NA + idx) * 16);
        float4 v = rv[c4];
        if (c4 == 0) {
            float hw = __fmul_rn(v.z, 0.5f), hh = __fmul_rn(v.w, 0.5f);
            o = make_float4(__fsub_rn(v.x, hw), __fsub_rn(v.y, hh),
                            __fadd_rn(v.x, hw), __fadd_rn(v.y, hh));
        } else if (c4 == 1) {
            o = make_float4(__uint_as_float((unsigned)(key >> 32)), v.y, v.z, v.w);
        } else if (c4 == 2) {
            o = v;
        } else {
            o = make_float4(v.x, v.y, v.z, 0.f);
        }
    }
    out[gid] = o;
}

// ---------------- launch ----------------
extern "C" void kernel_launch(void* const* d_in, const int* in_sizes, int n_in,
                              void* d_out, int out_size, void* d_ws, size_t ws_size,
                              hipStream_t stream) {
    (void)in_sizes; (void)n_in; (void)out_size; (void)ws_size;
    const float* pred = (const float*)d_in[0];
    char* ws = (char*)d_ws;
    // layout (bytes):
    unsigned* cand32   = (unsigned*)(ws + 0);          // 8*100800*4 = 3,225,600
    u64*      comp     = (u64*)     (ws + 3225600);    // 8*4096*8   =   262,144
    u64*      sel      = (u64*)     (ws + 3487744);    // 8*2048*8   =   131,072
    float4*   boxes    = (float4*)  (ws + 3618816);    // 8*2048*16  =   262,144
    u64*      maskT    = (u64*)     (ws + 3880960);    // 8*32*2048*8= 4,194,304
    u64*      keepmask = (u64*)     (ws + 8075264);    // 8*32*8     =     2,048
    int*      histb    = (int*)     (ws + 8077312);    // 8*99*64*4  =   202,752
    int*      pos      = (int*)     (ws + 8280064);    // 32
    int*      cut      = (int*)     (ws + 8280096);    // 32
    float4*   out      = (float4*)d_out;

    hipLaunchKernelGGL(k1_scan,    dim3(NBLK1, NIMG),            dim3(256),  0, stream, pred, cand32, histb);
    hipLaunchKernelGGL(k2a_cutoff, dim3(NIMG),                   dim3(64),   0, stream, histb, cut, pos);
    hipLaunchKernelGGL(k2b_compact,dim3(NBLK1, NIMG),            dim3(1024), 0, stream, cand32, cut, comp, pos);
    hipLaunchKernelGGL(k2c_rank,   dim3(NIMG),                   dim3(1024), 0, stream, comp, pos, pred, sel, boxes);
    hipLaunchKernelGGL(k4_masks,   dim3(64, NIMG),               dim3(1024), 0, stream, boxes, maskT);
    hipLaunchKernelGGL(k5_nms,     dim3(NIMG),                   dim3(1024), 0, stream, sel, maskT, keepmask);
    hipLaunchKernelGGL(k6_out,     dim3(NIMG * TOPK * 4 / 256),  dim3(256),  0, stream, pred, sel, keepmask, out);
}